// Round 11
// baseline (692.459 us; speedup 1.0000x reference)
//
#include <hip/hip_runtime.h>
#include <math.h>

// B=4, N=4096, C=128, DOUT=256, H=W=64 (conv out 32x32), M=1024, K=5.
#define NB 4
#define NT 4096
#define CI 128
#define DOUT 256
#define HWI 4096
#define HWO 1024
#define MC 1024
#define EPS_F 1e-6f

typedef unsigned short u16;
typedef __attribute__((ext_vector_type(8))) short bf16x8;
typedef __attribute__((ext_vector_type(4))) float f32x4;

// ---------------- workspace layout (bytes) ----------------
// zero zone:
static const size_t OFF_XMAP  = 0;                          // 8388608
static const size_t OFF_CNT   = OFF_XMAP + 8388608;         // 65536
static const size_t OFF_TOT   = OFF_CNT  + 65536;           // 65536
static const size_t OFF_ALLW  = OFF_TOT  + 65536;           // 16384
static const size_t OFF_VMAX  = OFF_ALLW + 16384;           // 256
static const size_t OFF_AWDM  = OFF_VMAX + 256;             // 256
static const size_t ZERO_BYTES= OFF_AWDM + 256;
// non-zeroed:
static const size_t OFF_YMAP  = ZERO_BYTES;                 // 4194304
static const size_t OFF_XT    = OFF_YMAP + 4194304;         // 16777216
static const size_t OFF_SQ    = OFF_XT + 16777216;          // 65536
static const size_t OFF_DEN   = OFF_SQ + 65536;
static const size_t OFF_SCORE = OFF_DEN + 65536;
static const size_t OFF_WT    = OFF_SCORE + 65536;
static const size_t OFF_AWD   = OFF_WT + 65536;
static const size_t OFF_IDXD  = OFF_AWD + 65536;            // 16384
static const size_t OFF_IDXC  = OFF_IDXD + 16384;           // 65536
static const size_t OFF_INV   = OFF_IDXC + 65536;           // 65536 (init in topk)
static const size_t OFF_WTR   = OFF_INV + 65536;            // 1179648 (wT[1152][256])
static const size_t OFF_SWT   = OFF_WTR + 1179648;          // 131072 (swT[128][256])
static const size_t OFF_P     = OFF_SWT + 131072;           // 18874368 (P dead after conv -> Dpart aliases)
static const size_t OFF_XH    = OFF_P + 18874368;           // 8388608 (bf16 hi)
static const size_t OFF_XM    = OFF_XH + 8388608;           // 8388608 (bf16 mid)
static const size_t OFF_XL    = OFF_XM + 8388608;           // 8388608 (bf16 lo)
// G eliminated (r11). Small cluster buffers live where G used to start:
static const size_t OFF_PP    = OFF_XL + 8388608;           // Ppart: NB*NT*32*4 = 2MB
static const size_t OFF_APD   = OFF_PP + (size_t)NB*NT*32*4;   // NB*NT*8*4 = 512KB
static const size_t OFF_APM   = OFF_APD + (size_t)NB*NT*8*4;   // 512KB
// Dpart: [b][4096 rows][32 tiles][6] floats = 3MB/slice x4 = 12.6MB, aliases OFF_P.
static const size_t DPSTRIDE  = (size_t)NT*32*6;            // floats per slice
static const size_t PPSTRIDE  = (size_t)NT*32;              // floats per slice

// ---------------- helpers ----------------
__device__ __forceinline__ float waveSum(float v){
#pragma unroll
  for (int m = 1; m < 64; m <<= 1) v += __shfl_xor(v, m, 64);
  return v;
}
__device__ __forceinline__ float blockSum256(float v, float* red){
  v = waveSum(v);
  int lane = threadIdx.x & 63, wid = threadIdx.x >> 6;
  __syncthreads();
  if (lane == 0) red[wid] = v;
  __syncthreads();
  return red[0] + red[1] + red[2] + red[3];
}
__device__ __forceinline__ void merge5(float& a0, float& a1, float& a2, float& a3, float& a4,
                                       float b0, float b1, float b2, float b3, float b4){
  float l0=a0,l1=a1,l2=a2,l3=fminf(a3,b4),l4=fminf(a4,b3),l5=b2,l6=b1,l7=b0;
  float t0=fminf(l0,l4), t4=fmaxf(l0,l4);
  float t1=fminf(l1,l5), t5=fmaxf(l1,l5);
  float t2=fminf(l2,l6), t6=fmaxf(l2,l6);
  float t3=fminf(l3,l7), t7=fmaxf(l3,l7);
  float u0=fminf(t0,t2), u2=fmaxf(t0,t2);
  float u1=fminf(t1,t3), u3=fmaxf(t1,t3);
  float u4=fminf(t4,t6);
  float u5=fminf(t5,t7);
  a0=fminf(u0,u1); a1=fmaxf(u0,u1);
  a2=fminf(u2,u3); a3=fmaxf(u2,u3);
  a4=fminf(u4,u5);
}
__device__ __forceinline__ void ins5(float v, float& t0, float& t1, float& t2, float& t3, float& t4){
  t4 = fminf(t4, v);
  float a;
  a = fminf(t3,t4); t4 = fmaxf(t3,t4); t3 = a;
  a = fminf(t2,t3); t3 = fmaxf(t2,t3); t2 = a;
  a = fminf(t1,t2); t2 = fmaxf(t1,t2); t1 = a;
  a = fminf(t0,t1); t1 = fmaxf(t0,t1); t0 = a;
}
__device__ __forceinline__ int grid_cell(float lx, float ly, int dim){
  lx = (fminf(fmaxf(lx, -1.f), 1.f) + 1.f) * 0.5f;
  ly = (fminf(fmaxf(ly, -1.f), 1.f) + 1.f) * 0.5f;
  float s = (float)(dim - 1);
  int col = (int)rintf(lx * s); col = min(max(col, 0), dim - 1);
  int row = (int)rintf(ly * s); row = min(max(row, 0), dim - 1);
  return row * dim + col;
}

// ---------------- front-end kernels ----------------
__global__ __launch_bounds__(256) void t2m_scatter(const float* __restrict__ x,
                                                   const float* __restrict__ loc,
                                                   const int* __restrict__ idx_agg,
                                                   const float* __restrict__ aggw,
                                                   float* __restrict__ xmap, float* __restrict__ cnt,
                                                   float* __restrict__ tot){
  int lin = blockIdx.x * 256 + threadIdx.x;
  int c  = lin & 127;
  int bn = lin >> 7;
  int b  = bn >> 12;
  float lx = loc[(size_t)bn*2 + 0];
  float ly = loc[(size_t)bn*2 + 1];
  int cell = grid_cell(lx, ly, 64);
  int ia = idx_agg[bn];
  float val = x[((size_t)(b*NT + ia))*CI + c];
  atomicAdd(&xmap[((size_t)(b*HWI + cell))*CI + c], val);
  if (c == 0) atomicAdd(&cnt[b*HWI + cell], 1.0f);
  if (c == 1) atomicAdd(&tot[b*NT + ia], aggw[bn]);
}

// fused weight prep: wT[k][d] = conv_w[d][k]; swT[c][d] = skip_w[d][c]
__global__ __launch_bounds__(256) void wprep_kernel(const float* __restrict__ cw, const float* __restrict__ sw,
                                                    float* __restrict__ wT, float* __restrict__ swT){
  int lin = blockIdx.x * 256 + threadIdx.x;
  if (lin < 1152*256){
    int k = lin >> 8, d = lin & 255;
    wT[lin] = cw[(size_t)d*1152 + k];
  } else {
    int i = lin - 1152*256;
    int c = i >> 8, d = i & 255;
    swT[i] = sw[d*128 + c];
  }
}

__global__ __launch_bounds__(256) void im2col_kernel(const float* __restrict__ xmap,
                                                     const float* __restrict__ cnt,
                                                     float* __restrict__ P){
  int tid = threadIdx.x;
  int c = tid & 127, n2 = tid >> 7;
  int n = blockIdx.x * 2 + n2;
  int b = n >> 10, rem = n & 1023;
  int oh = rem >> 5, ow = rem & 31;
  const float* xb = xmap + (size_t)b*HWI*CI;
  const float* cb_ = cnt + (size_t)b*HWI;
  float* prow = P + (size_t)n*1152 + c*9;
#pragma unroll
  for (int kh = 0; kh < 3; ++kh){
    int ih = oh*2 - 1 + kh;
#pragma unroll
    for (int kw = 0; kw < 3; ++kw){
      int iw = ow*2 - 1 + kw;
      bool inb = (ih >= 0) && (ih < 64) && (iw >= 0) && (iw < 64);
      float v = 0.f;
      if (inb){
        int cell = ih*64 + iw;
        v = xb[(size_t)cell*CI + c] / (cb_[cell] + EPS_F);
      }
      prow[kh*3 + kw] = v;
    }
  }
}

// conv GEMM: 64(n) x 32(d) tiles. Grid (64 n0, 8 d0) for A-panel L2 locality.
__global__ __launch_bounds__(256) void conv_gemm(const float* __restrict__ P,
                                                 const float* __restrict__ wT,
                                                 const float* __restrict__ cb,
                                                 float* __restrict__ ymap){
  __shared__ float As[16][64];
  __shared__ float Bs[16][32];
  int n0 = blockIdx.x * 64, d0 = blockIdx.y * 32;
  int tid = threadIdx.x;
  int tx = tid & 15, ty = tid >> 4;
  int ln = tid & 63, kq = tid >> 6;
  int bkr = tid >> 3, bc4 = (tid & 7) * 4;
  float4 pav = *(const float4*)(P + (size_t)(n0+ln)*1152 + kq*4);
  float4 pbv;
  if (tid < 128) pbv = *(const float4*)(wT + (size_t)bkr*256 + d0 + bc4);
  float acc[4][2] = {{0}};
  for (int kt = 0; kt < 72; ++kt){
    __syncthreads();
    As[kq*4+0][ln]=pav.x; As[kq*4+1][ln]=pav.y; As[kq*4+2][ln]=pav.z; As[kq*4+3][ln]=pav.w;
    if (tid < 128) *(float4*)&Bs[bkr][bc4] = pbv;
    __syncthreads();
    if (kt < 71){
      int k2 = (kt + 1) * 16;
      pav = *(const float4*)(P + (size_t)(n0+ln)*1152 + k2 + kq*4);
      if (tid < 128) pbv = *(const float4*)(wT + (size_t)(k2 + bkr)*256 + d0 + bc4);
    }
#pragma unroll
    for (int k = 0; k < 16; ++k){
      float ar[4];
      *(float4*)ar = *(const float4*)&As[k][ty*4];
      float b0 = Bs[k][tx*2], b1 = Bs[k][tx*2+1];
#pragma unroll
      for (int r = 0; r < 4; ++r){ acc[r][0] += ar[r]*b0; acc[r][1] += ar[r]*b1; }
    }
  }
  float c0 = cb[d0 + tx*2], c1 = cb[d0 + tx*2 + 1];
#pragma unroll
  for (int r = 0; r < 4; ++r){
    float2 o; o.x = acc[r][0] + c0; o.y = acc[r][1] + c1;
    *(float2*)(ymap + (size_t)(n0 + ty*4 + r)*DOUT + d0 + tx*2) = o;
  }
}

// xt = x @ skip_w.T via transposed weights (coalesced); c ascending -> bit-identical
__global__ __launch_bounds__(256) void skip_kernel(const float* __restrict__ x,
                                                   const float* __restrict__ swT,
                                                   float* __restrict__ xt){
  int rowbase = blockIdx.x * 8;
  int d = threadIdx.x;
  __shared__ float xr[8*128];
  ((float4*)xr)[d] = ((const float4*)(x + (size_t)rowbase*CI))[d];
  __syncthreads();
  float acc[8] = {0,0,0,0,0,0,0,0};
  for (int c = 0; c < 128; ++c){
    float w = swT[c*256 + d];
#pragma unroll
    for (int r = 0; r < 8; ++r) acc[r] += w * xr[r*128 + c];
  }
  for (int r = 0; r < 8; ++r) xt[(size_t)(rowbase + r)*DOUT + d] = acc[r];
}

__global__ __launch_bounds__(256) void m2t_scatter(const float* __restrict__ ymap,
                                                   const float* __restrict__ loc,
                                                   const int* __restrict__ idx_agg,
                                                   const float* __restrict__ aggw,
                                                   const float* __restrict__ tot,
                                                   float* __restrict__ xt){
  int bn = blockIdx.x;
  int d = threadIdx.x;
  int b = bn >> 12;
  float lx = loc[(size_t)bn*2 + 0];
  float ly = loc[(size_t)bn*2 + 1];
  int cell = grid_cell(lx, ly, 32);
  int ia = idx_agg[bn];
  float w = aggw[bn] / (tot[b*NT + ia] + EPS_F);
  float val = ymap[((size_t)(b*HWO + cell))*DOUT + d] * w;
  atomicAdd(&xt[((size_t)(b*NT + ia))*DOUT + d], val);
}

__global__ __launch_bounds__(256) void ln_kernel(float* __restrict__ xt,
                                                 const float* __restrict__ g,
                                                 const float* __restrict__ bta,
                                                 const float* __restrict__ cw,
                                                 const float* __restrict__ cb,
                                                 float* __restrict__ sq, float* __restrict__ wt){
  __shared__ float red[4];
  int row = blockIdx.x;
  int d = threadIdx.x;
  float v = xt[(size_t)row*DOUT + d];
  float mu = blockSum256(v, red) * (1.0f/256.0f);
  float xc = v - mu;
  float var = blockSum256(xc*xc, red) * (1.0f/256.0f);
  float rn = 1.0f / sqrtf(var + 1e-5f);
  float y = xc * rn * g[d] + bta[d];
  xt[(size_t)row*DOUT + d] = y;
  float s2 = blockSum256(y*y, red);
  float cf = blockSum256(y*cw[d], red);
  if (d == 0){ sq[row] = s2; wt[row] = expf(cf + cb[0]); }
}

// xsplit: exact 3-way bf16 truncation split xt = hi + mid + lo (24 mantissa bits).
__global__ __launch_bounds__(256) void xsplit_kernel(const float* __restrict__ xt,
                                                     u16* __restrict__ xh,
                                                     u16* __restrict__ xm,
                                                     u16* __restrict__ xl){
  int idx = blockIdx.x*256 + threadIdx.x;
  float2 v = *(const float2*)(xt + (size_t)idx*2);
  unsigned ph, pm, pl;
  {
    unsigned u = __float_as_uint(v.x);
    unsigned h0 = u >> 16;
    float r1 = v.x - __uint_as_float(u & 0xFFFF0000u);
    unsigned u1 = __float_as_uint(r1);
    unsigned m0 = u1 >> 16;
    float r2 = r1 - __uint_as_float(u1 & 0xFFFF0000u);
    unsigned l0 = __float_as_uint(r2) >> 16;
    unsigned u2 = __float_as_uint(v.y);
    unsigned h1 = u2 >> 16;
    float s1 = v.y - __uint_as_float(u2 & 0xFFFF0000u);
    unsigned u3 = __float_as_uint(s1);
    unsigned m1 = u3 >> 16;
    float s2 = s1 - __uint_as_float(u3 & 0xFFFF0000u);
    unsigned l1 = __float_as_uint(s2) >> 16;
    ph = h0 | (h1 << 16); pm = m0 | (m1 << 16); pl = l0 | (l1 << 16);
  }
  *(unsigned*)(xh + (size_t)idx*2) = ph;
  *(unsigned*)(xm + (size_t)idx*2) = pm;
  *(unsigned*)(xl + (size_t)idx*2) = pl;
}

// ---------------- clustering (G never materialized, r11) ----------------
// dens_mfma: r10 gram_mfma with the G stores DELETED. bf16x3 MFMA tiles
// (6 cross terms, fp32 accum); density partials only. acc values and all
// reductions identical to r10 -> density/vmax bit-identical to r10.
__global__ __launch_bounds__(256) void dens_mfma(const u16* __restrict__ xh,
                                                 const u16* __restrict__ xm,
                                                 const u16* __restrict__ xl,
                                                 const float* __restrict__ sq,
                                                 float* __restrict__ Dpart){
  __shared__ u16 usmem[24576];
  u16* Au = usmem;
  u16* Bu = usmem + 12288;
  int b = blockIdx.y;
  float* Dp = Dpart + (size_t)b*DPSTRIDE;
  int t = blockIdx.x;
  int ti = 0, accu = 0;
  while (accu + ti + 1 <= t){ accu += ti + 1; ++ti; }
  int tj = t - accu;
  int i0 = ti*128, j0 = tj*128;
  int tid = threadIdx.x;
  int w = tid >> 6, l = tid & 63;
  int lrow = l & 15, lg = l >> 4;
  int li = tid & 127, kq = tid >> 7;
  const size_t base = (size_t)b*NT*256;
  size_t arow = base + (size_t)(i0 + li)*256 + kq*16;
  size_t brow = base + (size_t)(j0 + li)*256 + kq*16;
  const u16* csrc[3] = {xh, xm, xl};
  int ga0 = ((li*4 + kq*2 + 0) ^ (li & 7)) * 8;
  int ga1 = ((li*4 + kq*2 + 1) ^ (li & 7)) * 8;
  f32x4 acc[2][8];
  f32x4 z; z[0]=0.f; z[1]=0.f; z[2]=0.f; z[3]=0.f;
#pragma unroll
  for (int mr = 0; mr < 2; ++mr)
#pragma unroll
    for (int n0 = 0; n0 < 8; ++n0) acc[mr][n0] = z;
  for (int kc = 0; kc < 8; ++kc){
    int k0 = kc*32;
    __syncthreads();
#pragma unroll
    for (int c = 0; c < 3; ++c){
      const u16* s = csrc[c];
      bf16x8 a0 = *(const bf16x8*)(s + arow + k0);
      bf16x8 a1 = *(const bf16x8*)(s + arow + k0 + 8);
      bf16x8 b0 = *(const bf16x8*)(s + brow + k0);
      bf16x8 b1 = *(const bf16x8*)(s + brow + k0 + 8);
      *(bf16x8*)(Au + c*4096 + ga0) = a0;
      *(bf16x8*)(Au + c*4096 + ga1) = a1;
      *(bf16x8*)(Bu + c*4096 + ga0) = b0;
      *(bf16x8*)(Bu + c*4096 + ga1) = b1;
    }
    __syncthreads();
    bf16x8 af[2][3];
#pragma unroll
    for (int mr = 0; mr < 2; ++mr){
      int row = w*32 + mr*16 + lrow;
      int off = ((row*4 + lg) ^ (row & 7)) * 8;
#pragma unroll
      for (int c = 0; c < 3; ++c)
        af[mr][c] = *(const bf16x8*)(Au + c*4096 + off);
    }
#pragma unroll
    for (int n0 = 0; n0 < 8; ++n0){
      int rowb = n0*16 + lrow;
      int offb = ((rowb*4 + lg) ^ (rowb & 7)) * 8;
      bf16x8 bh = *(const bf16x8*)(Bu + 0*4096 + offb);
      bf16x8 bm = *(const bf16x8*)(Bu + 1*4096 + offb);
      bf16x8 bl = *(const bf16x8*)(Bu + 2*4096 + offb);
#pragma unroll
      for (int mr = 0; mr < 2; ++mr){
        acc[mr][n0] = __builtin_amdgcn_mfma_f32_16x16x32_bf16(af[mr][0], bh, acc[mr][n0], 0, 0, 0);
        acc[mr][n0] = __builtin_amdgcn_mfma_f32_16x16x32_bf16(af[mr][0], bm, acc[mr][n0], 0, 0, 0);
        acc[mr][n0] = __builtin_amdgcn_mfma_f32_16x16x32_bf16(af[mr][1], bh, acc[mr][n0], 0, 0, 0);
        acc[mr][n0] = __builtin_amdgcn_mfma_f32_16x16x32_bf16(af[mr][1], bm, acc[mr][n0], 0, 0, 0);
        acc[mr][n0] = __builtin_amdgcn_mfma_f32_16x16x32_bf16(af[mr][0], bl, acc[mr][n0], 0, 0, 0);
        acc[mr][n0] = __builtin_amdgcn_mfma_f32_16x16x32_bf16(af[mr][2], bh, acc[mr][n0], 0, 0, 0);
      }
    }
  }
  const float* sqb2 = sq + b*NT;
  // i-side density partials
  {
    float sqj_c[8];
#pragma unroll
    for (int n0 = 0; n0 < 8; ++n0) sqj_c[n0] = sqb2[j0 + n0*16 + lrow];
#pragma unroll
    for (int mr = 0; mr < 2; ++mr)
#pragma unroll
      for (int r = 0; r < 4; ++r){
        int row = i0 + w*32 + mr*16 + lg*4 + r;
        float sqi_v = sqb2[row];
        float t0=INFINITY,t1=INFINITY,t2=INFINITY,t3=INFINITY,t4=INFINITY;
        float mx = 0.f;
#pragma unroll
        for (int n0 = 0; n0 < 8; ++n0){
          float v = fmaxf(sqi_v + sqj_c[n0] - 2.0f*acc[mr][n0][r], 0.0f);
          mx = fmaxf(mx, v);
          ins5(v,t0,t1,t2,t3,t4);
        }
#pragma unroll
        for (int m = 1; m < 16; m <<= 1){
          float b0=__shfl_xor(t0,m,64), b1=__shfl_xor(t1,m,64), b2=__shfl_xor(t2,m,64),
                b3=__shfl_xor(t3,m,64), b4=__shfl_xor(t4,m,64);
          merge5(t0,t1,t2,t3,t4,b0,b1,b2,b3,b4);
          mx = fmaxf(mx, __shfl_xor(mx,m,64));
        }
        if (lrow == 0){
          float* dpp = Dp + ((size_t)row*32 + tj)*6;
          dpp[0]=t0; dpp[1]=t1; dpp[2]=t2; dpp[3]=t3; dpp[4]=t4; dpp[5]=mx;
        }
      }
  }
  if (ti != tj){
    // j-side partials via LDS transpose chunks (no G store)
    float* T = (float*)usmem;
    int q = tid >> 3, u = tid & 7;
    float sqi_u[16];
#pragma unroll
    for (int e = 0; e < 16; ++e) sqi_u[e] = sqb2[i0 + u*16 + e];
#pragma unroll
    for (int cc = 0; cc < 4; ++cc){
      __syncthreads();
#pragma unroll
      for (int nn = 0; nn < 2; ++nn){
        int n0 = cc*2 + nn;
#pragma unroll
        for (int mr = 0; mr < 2; ++mr)
#pragma unroll
          for (int r = 0; r < 4; ++r)
            T[(nn*16 + lrow)*129 + w*32 + mr*16 + lg*4 + r] = acc[mr][n0][r];
      }
      __syncthreads();
      const float* Trow = &T[q*129 + u*16];
      float gv[16];
#pragma unroll
      for (int e = 0; e < 16; ++e) gv[e] = Trow[e];
      int jr = j0 + cc*32 + q;
      float sqj_m = sqb2[jr];
      float t0=INFINITY,t1=INFINITY,t2=INFINITY,t3=INFINITY,t4=INFINITY;
      float mx = 0.f;
#pragma unroll
      for (int e = 0; e < 16; ++e){
        float v = fmaxf(sqj_m + sqi_u[e] - 2.0f*gv[e], 0.0f);
        mx = fmaxf(mx, v);
        ins5(v,t0,t1,t2,t3,t4);
      }
#pragma unroll
      for (int m = 1; m < 8; m <<= 1){
        float b0=__shfl_xor(t0,m,64), b1=__shfl_xor(t1,m,64), b2=__shfl_xor(t2,m,64),
              b3=__shfl_xor(t3,m,64), b4=__shfl_xor(t4,m,64);
        merge5(t0,t1,t2,t3,t4,b0,b1,b2,b3,b4);
        mx = fmaxf(mx, __shfl_xor(mx,m,64));
      }
      if (u == 0){
        float* dpp = Dp + ((size_t)jr*32 + ti)*6;
        dpp[0]=t0; dpp[1]=t1; dpp[2]=t2; dpp[3]=t3; dpp[4]=t4; dpp[5]=mx;
      }
    }
  }
}

// dens_merge: fold 32 sorted per-tile partials per row -> density + vmax (exact).
__global__ __launch_bounds__(256) void dens_merge(const float* __restrict__ Dpart,
                                                  float* __restrict__ density, int* __restrict__ vmax){
  int b = blockIdx.y;
  const float* Dp = Dpart + (size_t)b*DPSTRIDE;
  int row = blockIdx.x*256 + threadIdx.x;
  const float* p = Dp + (size_t)row*32*6;
  float t0=INFINITY,t1=INFINITY,t2=INFINITY,t3=INFINITY,t4=INFINITY;
  float mx = 0.f;
#pragma unroll 4
  for (int tt = 0; tt < 32; ++tt){
    merge5(t0,t1,t2,t3,t4, p[tt*6+0], p[tt*6+1], p[tt*6+2], p[tt*6+3], p[tt*6+4]);
    mx = fmaxf(mx, p[tt*6+5]);
  }
  float d0=sqrtf(t0)*0.0625f, d1=sqrtf(t1)*0.0625f, d2=sqrtf(t2)*0.0625f,
        d3=sqrtf(t3)*0.0625f, d4=sqrtf(t4)*0.0625f;
  float s = d0*d0; s += d1*d1; s += d2*d2; s += d3*d3; s += d4*d4;
  density[b*NT + row] = expf(-(s / 5.0f));
#pragma unroll
  for (int m = 1; m < 64; m <<= 1) mx = fmaxf(mx, __shfl_xor(mx, m, 64));
  if ((threadIdx.x & 63) == 0) atomicMax(vmax + b, __float_as_int(mx));
}

// parent_mfma: second tile pass (same skeleton); per-row min over candidates
// with den[cand] > den[row]. acc values identical to dens_mfma; fmin exact
// -> score bit-identical to the old G-reading parent_all.
__global__ __launch_bounds__(256) void parent_mfma(const u16* __restrict__ xh,
                                                   const u16* __restrict__ xm,
                                                   const u16* __restrict__ xl,
                                                   const float* __restrict__ sq,
                                                   const float* __restrict__ den,
                                                   float* __restrict__ Ppart){
  __shared__ u16 usmem[24576];
  u16* Au = usmem;
  u16* Bu = usmem + 12288;
  int b = blockIdx.y;
  float* Pp = Ppart + (size_t)b*PPSTRIDE;
  int t = blockIdx.x;
  int ti = 0, accu = 0;
  while (accu + ti + 1 <= t){ accu += ti + 1; ++ti; }
  int tj = t - accu;
  int i0 = ti*128, j0 = tj*128;
  int tid = threadIdx.x;
  int w = tid >> 6, l = tid & 63;
  int lrow = l & 15, lg = l >> 4;
  int li = tid & 127, kq = tid >> 7;
  const size_t base = (size_t)b*NT*256;
  size_t arow = base + (size_t)(i0 + li)*256 + kq*16;
  size_t brow = base + (size_t)(j0 + li)*256 + kq*16;
  const u16* csrc[3] = {xh, xm, xl};
  int ga0 = ((li*4 + kq*2 + 0) ^ (li & 7)) * 8;
  int ga1 = ((li*4 + kq*2 + 1) ^ (li & 7)) * 8;
  f32x4 acc[2][8];
  f32x4 z; z[0]=0.f; z[1]=0.f; z[2]=0.f; z[3]=0.f;
#pragma unroll
  for (int mr = 0; mr < 2; ++mr)
#pragma unroll
    for (int n0 = 0; n0 < 8; ++n0) acc[mr][n0] = z;
  for (int kc = 0; kc < 8; ++kc){
    int k0 = kc*32;
    __syncthreads();
#pragma unroll
    for (int c = 0; c < 3; ++c){
      const u16* s = csrc[c];
      bf16x8 a0 = *(const bf16x8*)(s + arow + k0);
      bf16x8 a1 = *(const bf16x8*)(s + arow + k0 + 8);
      bf16x8 b0 = *(const bf16x8*)(s + brow + k0);
      bf16x8 b1 = *(const bf16x8*)(s + brow + k0 + 8);
      *(bf16x8*)(Au + c*4096 + ga0) = a0;
      *(bf16x8*)(Au + c*4096 + ga1) = a1;
      *(bf16x8*)(Bu + c*4096 + ga0) = b0;
      *(bf16x8*)(Bu + c*4096 + ga1) = b1;
    }
    __syncthreads();
    bf16x8 af[2][3];
#pragma unroll
    for (int mr = 0; mr < 2; ++mr){
      int row = w*32 + mr*16 + lrow;
      int off = ((row*4 + lg) ^ (row & 7)) * 8;
#pragma unroll
      for (int c = 0; c < 3; ++c)
        af[mr][c] = *(const bf16x8*)(Au + c*4096 + off);
    }
#pragma unroll
    for (int n0 = 0; n0 < 8; ++n0){
      int rowb = n0*16 + lrow;
      int offb = ((rowb*4 + lg) ^ (rowb & 7)) * 8;
      bf16x8 bh = *(const bf16x8*)(Bu + 0*4096 + offb);
      bf16x8 bm = *(const bf16x8*)(Bu + 1*4096 + offb);
      bf16x8 bl = *(const bf16x8*)(Bu + 2*4096 + offb);
#pragma unroll
      for (int mr = 0; mr < 2; ++mr){
        acc[mr][n0] = __builtin_amdgcn_mfma_f32_16x16x32_bf16(af[mr][0], bh, acc[mr][n0], 0, 0, 0);
        acc[mr][n0] = __builtin_amdgcn_mfma_f32_16x16x32_bf16(af[mr][0], bm, acc[mr][n0], 0, 0, 0);
        acc[mr][n0] = __builtin_amdgcn_mfma_f32_16x16x32_bf16(af[mr][1], bh, acc[mr][n0], 0, 0, 0);
        acc[mr][n0] = __builtin_amdgcn_mfma_f32_16x16x32_bf16(af[mr][1], bm, acc[mr][n0], 0, 0, 0);
        acc[mr][n0] = __builtin_amdgcn_mfma_f32_16x16x32_bf16(af[mr][0], bl, acc[mr][n0], 0, 0, 0);
        acc[mr][n0] = __builtin_amdgcn_mfma_f32_16x16x32_bf16(af[mr][2], bh, acc[mr][n0], 0, 0, 0);
      }
    }
  }
  const float* sqb2 = sq + b*NT;
  const float* denb = den + b*NT;
  // i-side: rows in ti-block, candidates = tj-block cols
  {
    float sqj_c[8], dnj_c[8];
#pragma unroll
    for (int n0 = 0; n0 < 8; ++n0){
      sqj_c[n0] = sqb2[j0 + n0*16 + lrow];
      dnj_c[n0] = denb[j0 + n0*16 + lrow];
    }
#pragma unroll
    for (int mr = 0; mr < 2; ++mr)
#pragma unroll
      for (int r = 0; r < 4; ++r){
        int row = i0 + w*32 + mr*16 + lg*4 + r;
        float di = denb[row];
        float sqi_v = sqb2[row];
        float mn = INFINITY;
#pragma unroll
        for (int n0 = 0; n0 < 8; ++n0){
          float v = fmaxf(sqi_v + sqj_c[n0] - 2.0f*acc[mr][n0][r], 0.0f);
          mn = fminf(mn, (dnj_c[n0] > di) ? v : INFINITY);
        }
#pragma unroll
        for (int m = 1; m < 16; m <<= 1) mn = fminf(mn, __shfl_xor(mn, m, 64));
        if (lrow == 0) Pp[(size_t)row*32 + tj] = mn;
      }
  }
  if (ti != tj){
    float* T = (float*)usmem;
    int q = tid >> 3, u = tid & 7;
    float sqi_u[16], dni_u[16];
#pragma unroll
    for (int e = 0; e < 16; ++e){
      sqi_u[e] = sqb2[i0 + u*16 + e];
      dni_u[e] = denb[i0 + u*16 + e];
    }
#pragma unroll
    for (int cc = 0; cc < 4; ++cc){
      __syncthreads();
#pragma unroll
      for (int nn = 0; nn < 2; ++nn){
        int n0 = cc*2 + nn;
#pragma unroll
        for (int mr = 0; mr < 2; ++mr)
#pragma unroll
          for (int r = 0; r < 4; ++r)
            T[(nn*16 + lrow)*129 + w*32 + mr*16 + lg*4 + r] = acc[mr][n0][r];
      }
      __syncthreads();
      const float* Trow = &T[q*129 + u*16];
      int jr = j0 + cc*32 + q;
      float dj = denb[jr];
      float sqj_m = sqb2[jr];
      float mn = INFINITY;
#pragma unroll
      for (int e = 0; e < 16; ++e){
        float v = fmaxf(sqj_m + sqi_u[e] - 2.0f*Trow[e], 0.0f);
        mn = fminf(mn, (dni_u[e] > dj) ? v : INFINITY);
      }
#pragma unroll
      for (int m = 1; m < 8; m <<= 1) mn = fminf(mn, __shfl_xor(mn, m, 64));
      if (u == 0) Pp[(size_t)jr*32 + ti] = mn;
    }
  }
}

// parent_merge: fold 32 partial mins per row -> score.
__global__ __launch_bounds__(256) void parent_merge(const float* __restrict__ Ppart,
                                                    const float* __restrict__ density,
                                                    const int* __restrict__ vmax,
                                                    float* __restrict__ score){
  int b = blockIdx.y;
  int row = blockIdx.x*256 + threadIdx.x;
  const float* p = Ppart + (size_t)b*PPSTRIDE + (size_t)row*32;
  float mn = INFINITY;
#pragma unroll 4
  for (int tt = 0; tt < 32; ++tt) mn = fminf(mn, p[tt]);
  float dmax = sqrtf(__int_as_float(vmax[b])) * 0.0625f;
  float dp = isinf(mn) ? dmax : sqrtf(mn) * 0.0625f;
  score[b*NT + row] = dp * density[b*NT + row];
}

// ---------------- topk: hybrid bitonic sort 4096 (score desc, idx asc) ----------------
__device__ __forceinline__ bool kv_lt(float s1, int a1, float s2, int a2){
  return (s1 > s2) || (s1 == s2 && a1 < a2);
}
#define KV_CMPX(sx,ax,sy,ay,up) do{ bool _l = kv_lt(sx,ax,sy,ay); \
  if (_l != (up)) { float _ts=sx; sx=sy; sy=_ts; int _ta=ax; ax=ay; ay=_ta; } }while(0)
#define KV_TAKE(sx,ax,ps,pa,eqd) do{ bool _keep = kv_lt(sx,ax,ps,pa) == (eqd); \
  if(!_keep){ sx=(ps); ax=(pa); } }while(0)

__global__ __launch_bounds__(1024) void topk_all(const float* __restrict__ score, int* __restrict__ idx_down,
                                                 int* __restrict__ inv){
  __shared__ float ss[4096];
  __shared__ int ii[4096];
  int b = blockIdx.x;
  int t = threadIdx.x;
  float s0,s1,s2,s3; int a0,a1,a2,a3;
  {
    float4 v = *(const float4*)(score + b*NT + 4*t);
    s0=v.x; s1=v.y; s2=v.z; s3=v.w;
    a0=4*t; a1=4*t+1; a2=4*t+2; a3=4*t+3;
    int4 mi; mi.x=-1; mi.y=-1; mi.z=-1; mi.w=-1;
    *(int4*)(inv + b*NT + 4*t) = mi;
  }
  for (int k = 2; k <= 4096; k <<= 1){
    bool upT = ((4*t) & k) == 0;
    for (int j = k >> 1; j >= 256; j >>= 1){
      __syncthreads();
      float4 sv; sv.x=s0; sv.y=s1; sv.z=s2; sv.w=s3;
      int4 av; av.x=a0; av.y=a1; av.z=a2; av.w=a3;
      *(float4*)&ss[4*t] = sv;
      *(int4*)&ii[4*t] = av;
      __syncthreads();
      int pt = t ^ (j >> 2);
      bool eqd = ((t & (j >> 2)) == 0) == upT;
      float4 ps = *(const float4*)&ss[4*pt];
      int4  pa = *(const int4*)&ii[4*pt];
      KV_TAKE(s0,a0,ps.x,pa.x,eqd);
      KV_TAKE(s1,a1,ps.y,pa.y,eqd);
      KV_TAKE(s2,a2,ps.z,pa.z,eqd);
      KV_TAKE(s3,a3,ps.w,pa.w,eqd);
    }
    int jhi = (k >> 1) < 128 ? (k >> 1) : 128;
    for (int j = jhi; j >= 4; j >>= 1){
      int dl = j >> 2;
      bool eqd = ((t & dl) == 0) == upT;
      { float ps=__shfl_xor(s0,dl,64); int pa=__shfl_xor(a0,dl,64); KV_TAKE(s0,a0,ps,pa,eqd); }
      { float ps=__shfl_xor(s1,dl,64); int pa=__shfl_xor(a1,dl,64); KV_TAKE(s1,a1,ps,pa,eqd); }
      { float ps=__shfl_xor(s2,dl,64); int pa=__shfl_xor(a2,dl,64); KV_TAKE(s2,a2,ps,pa,eqd); }
      { float ps=__shfl_xor(s3,dl,64); int pa=__shfl_xor(a3,dl,64); KV_TAKE(s3,a3,ps,pa,eqd); }
    }
    if (k >= 4){
      KV_CMPX(s0,a0,s2,a2,upT);
      KV_CMPX(s1,a1,s3,a3,upT);
      KV_CMPX(s0,a0,s1,a1,upT);
      KV_CMPX(s2,a2,s3,a3,upT);
    } else {
      KV_CMPX(s0,a0,s1,a1,true);
      KV_CMPX(s2,a2,s3,a3,false);
    }
  }
  __syncthreads();
  if (t < 256){
    idx_down[b*MC + 4*t + 0] = a0; inv[b*NT + a0] = 4*t + 0;
    idx_down[b*MC + 4*t + 1] = a1; inv[b*NT + a1] = 4*t + 1;
    idx_down[b*MC + 4*t + 2] = a2; inv[b*NT + a2] = 4*t + 2;
    idx_down[b*MC + 4*t + 3] = a3; inv[b*NT + a3] = 4*t + 3;
  }
}

// assign_mfma: recompute center-vs-token distances (1024x4096, 1/4 gram work).
// Block = (ct center-tile 0..7, jt col-tile 0..31). Lexicographic (d, m) min
// per column, matching assign_all's ascending-m strict-< loop. Distances are
// the same 6-term MFMA accumulation; for pairs previously stored via the
// mirror path the term ORDER differs -> <=1-ulp reorder noise (r2 precedent).
__global__ __launch_bounds__(256) void assign_mfma(const u16* __restrict__ xh,
                                                   const u16* __restrict__ xm,
                                                   const u16* __restrict__ xl,
                                                   const float* __restrict__ sq,
                                                   const int* __restrict__ idx_down,
                                                   float* __restrict__ Apd, int* __restrict__ Apm){
  __shared__ u16 usmem[24576];
  __shared__ int idbs[128];
  u16* Au = usmem;
  u16* Bu = usmem + 12288;
  int b = blockIdx.y;
  int ct = blockIdx.x >> 5;
  int jt = blockIdx.x & 31;
  int j0 = jt*128;
  int tid = threadIdx.x;
  int w = tid >> 6, l = tid & 63;
  int lrow = l & 15, lg = l >> 4;
  int li = tid & 127, kq = tid >> 7;
  if (tid < 128) idbs[tid] = idx_down[b*MC + ct*128 + tid];
  __syncthreads();
  const size_t base = (size_t)b*NT*256;
  size_t arow = base + (size_t)idbs[li]*256 + kq*16;
  size_t brow = base + (size_t)(j0 + li)*256 + kq*16;
  const u16* csrc[3] = {xh, xm, xl};
  int ga0 = ((li*4 + kq*2 + 0) ^ (li & 7)) * 8;
  int ga1 = ((li*4 + kq*2 + 1) ^ (li & 7)) * 8;
  f32x4 acc[2][8];
  f32x4 z; z[0]=0.f; z[1]=0.f; z[2]=0.f; z[3]=0.f;
#pragma unroll
  for (int mr = 0; mr < 2; ++mr)
#pragma unroll
    for (int n0 = 0; n0 < 8; ++n0) acc[mr][n0] = z;
  for (int kc = 0; kc < 8; ++kc){
    int k0 = kc*32;
    __syncthreads();
#pragma unroll
    for (int c = 0; c < 3; ++c){
      const u16* s = csrc[c];
      bf16x8 a0 = *(const bf16x8*)(s + arow + k0);
      bf16x8 a1 = *(const bf16x8*)(s + arow + k0 + 8);
      bf16x8 b0 = *(const bf16x8*)(s + brow + k0);
      bf16x8 b1 = *(const bf16x8*)(s + brow + k0 + 8);
      *(bf16x8*)(Au + c*4096 + ga0) = a0;
      *(bf16x8*)(Au + c*4096 + ga1) = a1;
      *(bf16x8*)(Bu + c*4096 + ga0) = b0;
      *(bf16x8*)(Bu + c*4096 + ga1) = b1;
    }
    __syncthreads();
    bf16x8 af[2][3];
#pragma unroll
    for (int mr = 0; mr < 2; ++mr){
      int row = w*32 + mr*16 + lrow;
      int off = ((row*4 + lg) ^ (row & 7)) * 8;
#pragma unroll
      for (int c = 0; c < 3; ++c)
        af[mr][c] = *(const bf16x8*)(Au + c*4096 + off);
    }
#pragma unroll
    for (int n0 = 0; n0 < 8; ++n0){
      int rowb = n0*16 + lrow;
      int offb = ((rowb*4 + lg) ^ (rowb & 7)) * 8;
      bf16x8 bh = *(const bf16x8*)(Bu + 0*4096 + offb);
      bf16x8 bm = *(const bf16x8*)(Bu + 1*4096 + offb);
      bf16x8 bl = *(const bf16x8*)(Bu + 2*4096 + offb);
#pragma unroll
      for (int mr = 0; mr < 2; ++mr){
        acc[mr][n0] = __builtin_amdgcn_mfma_f32_16x16x32_bf16(af[mr][0], bh, acc[mr][n0], 0, 0, 0);
        acc[mr][n0] = __builtin_amdgcn_mfma_f32_16x16x32_bf16(af[mr][0], bm, acc[mr][n0], 0, 0, 0);
        acc[mr][n0] = __builtin_amdgcn_mfma_f32_16x16x32_bf16(af[mr][1], bh, acc[mr][n0], 0, 0, 0);
        acc[mr][n0] = __builtin_amdgcn_mfma_f32_16x16x32_bf16(af[mr][1], bm, acc[mr][n0], 0, 0, 0);
        acc[mr][n0] = __builtin_amdgcn_mfma_f32_16x16x32_bf16(af[mr][0], bl, acc[mr][n0], 0, 0, 0);
        acc[mr][n0] = __builtin_amdgcn_mfma_f32_16x16x32_bf16(af[mr][2], bh, acc[mr][n0], 0, 0, 0);
      }
    }
  }
  const float* sqb2 = sq + b*NT;
  float sqj_c[8];
#pragma unroll
  for (int n0 = 0; n0 < 8; ++n0) sqj_c[n0] = sqb2[j0 + n0*16 + lrow];
  float bd[8]; int bm2[8];
#pragma unroll
  for (int n0 = 0; n0 < 8; ++n0){ bd[n0] = INFINITY; bm2[n0] = 0x7fffffff; }
#pragma unroll
  for (int mr = 0; mr < 2; ++mr)
#pragma unroll
    for (int r = 0; r < 4; ++r){
      int ml = w*32 + mr*16 + lg*4 + r;
      float sqi_v = sqb2[idbs[ml]];
#pragma unroll
      for (int n0 = 0; n0 < 8; ++n0){
        float v = fmaxf(sqi_v + sqj_c[n0] - 2.0f*acc[mr][n0][r], 0.0f);
        float d = sqrtf(v) * 0.0625f;
        if (d < bd[n0] || (d == bd[n0] && ml < bm2[n0])){ bd[n0] = d; bm2[n0] = ml; }
      }
    }
#pragma unroll
  for (int m = 16; m < 64; m <<= 1)
#pragma unroll
    for (int n0 = 0; n0 < 8; ++n0){
      float od = __shfl_xor(bd[n0], m, 64);
      int   om = __shfl_xor(bm2[n0], m, 64);
      if (od < bd[n0] || (od == bd[n0] && om < bm2[n0])){ bd[n0] = od; bm2[n0] = om; }
    }
  __syncthreads();
  float* sd = (float*)usmem;               // [4][128] floats (2 KB)
  int*   sm = (int*)(usmem + 1024);        // [4][128] ints  (2 KB, byte 2048+)
  if (lg == 0){
#pragma unroll
    for (int n0 = 0; n0 < 8; ++n0){
      sd[w*128 + n0*16 + lrow] = bd[n0];
      sm[w*128 + n0*16 + lrow] = bm2[n0];
    }
  }
  __syncthreads();
  if (tid < 128){
    float d = sd[tid]; int m = sm[tid];
#pragma unroll
    for (int ww = 1; ww < 4; ++ww){
      float od = sd[ww*128 + tid]; int om = sm[ww*128 + tid];
      if (od < d || (od == d && om < m)){ d = od; m = om; }
    }
    int j = j0 + tid;
    Apd[((size_t)b*NT + j)*8 + ct] = d;
    Apm[((size_t)b*NT + j)*8 + ct] = ct*128 + m;
  }
}

// assign_merge: fold 8 center-tile partials (lexicographic, ascending ct = ascending m).
__global__ __launch_bounds__(256) void assign_merge(const float* __restrict__ Apd, const int* __restrict__ Apm,
                                                    const int* __restrict__ inv, const float* __restrict__ wt,
                                                    int* __restrict__ idx_cluster, float* __restrict__ allw){
  int b = blockIdx.y;
  int j = blockIdx.x*256 + threadIdx.x;
  const float* pd = Apd + ((size_t)b*NT + j)*8;
  const int*   pm = Apm + ((size_t)b*NT + j)*8;
  float bdv = INFINITY; int bmv = 0x7fffffff;
#pragma unroll
  for (int ct = 0; ct < 8; ++ct){
    float d = pd[ct]; int m = pm[ct];
    if (d < bdv || (d == bdv && m < bmv)){ bdv = d; bmv = m; }
  }
  int iv = inv[b*NT + j];
  int fm = (iv >= 0) ? iv : bmv;
  idx_cluster[b*NT + j] = fm;
  atomicAdd(&allw[b*MC + fm], wt[b*NT + j]);
}

// ---------------- merge + outputs ----------------
__global__ __launch_bounds__(256) void xdown_kernel(const int* __restrict__ idx_cluster,
                                                    const float* __restrict__ wt, const float* __restrict__ allw,
                                                    const float* __restrict__ xt, float* __restrict__ out0){
  int bn = blockIdx.x;
  int d = threadIdx.x;
  int b = bn >> 12;
  int ic = idx_cluster[bn];
  float nw = wt[bn] / (allw[b*MC + ic] + EPS_F);
  float v = xt[(size_t)bn*DOUT + d] * nw;
  atomicAdd(&out0[((size_t)(b*MC + ic))*DOUT + d], v);
}
__global__ __launch_bounds__(256) void out12a_kernel(const int* __restrict__ idx_agg, const int* __restrict__ idx_cluster,
                                                     const float* __restrict__ aggw,
                                                     const float* __restrict__ wt, const float* __restrict__ allw,
                                                     float* __restrict__ awd, int* __restrict__ awdmax,
                                                     float* __restrict__ out1){
  __shared__ float red[4];
  int lin = blockIdx.x * 256 + threadIdx.x;
  int b = lin >> 12;
  int ia = idx_agg[lin];
  int ic = idx_cluster[b*NT + ia];
  out1[lin] = (float)ic;
  float nw = wt[b*NT + ia] / (allw[b*MC + ic] + EPS_F);
  float v = aggw[lin] * nw;
  awd[lin] = v;
  float wv = v;
#pragma unroll
  for (int m = 1; m < 64; m <<= 1) wv = fmaxf(wv, __shfl_xor(wv, m, 64));
  int lane = threadIdx.x & 63, wid = threadIdx.x >> 6;
  if (lane == 0) red[wid] = wv;
  __syncthreads();
  if (threadIdx.x == 0){
    float bm = fmaxf(fmaxf(red[0], red[1]), fmaxf(red[2], red[3]));
    atomicMax(&awdmax[b], __float_as_int(bm));
  }
}
__global__ __launch_bounds__(256) void out2_kernel(const float* __restrict__ awd, const int* __restrict__ awdmax,
                                                   float* __restrict__ out2){
  int lin = blockIdx.x * 256 + threadIdx.x;
  int b = lin >> 12;
  out2[lin] = awd[lin] / __int_as_float(awdmax[b]);
}

extern "C" void kernel_launch(void* const* d_in, const int* in_sizes, int n_in,
                              void* d_out, int out_size, void* d_ws, size_t ws_size,
                              hipStream_t stream) {
  const float* x      = (const float*)d_in[0];
  const float* loc    = (const float*)d_in[1];
  const int*   idxagg = (const int*)d_in[2];
  const float* aggw   = (const float*)d_in[3];
  const float* convw  = (const float*)d_in[7];
  const float* convb  = (const float*)d_in[8];
  const float* skipw  = (const float*)d_in[9];
  const float* lng    = (const float*)d_in[10];
  const float* lnb    = (const float*)d_in[11];
  const float* confw  = (const float*)d_in[12];
  const float* confb  = (const float*)d_in[13];

  char* ws = (char*)d_ws;
  float* w_xmap  = (float*)(ws + OFF_XMAP);
  float* w_cnt   = (float*)(ws + OFF_CNT);
  float* w_tot   = (float*)(ws + OFF_TOT);
  float* w_allw  = (float*)(ws + OFF_ALLW);
  int*   w_vmax  = (int*)  (ws + OFF_VMAX);
  int*   w_awdm  = (int*)  (ws + OFF_AWDM);
  float* w_ymap  = (float*)(ws + OFF_YMAP);
  float* w_xt    = (float*)(ws + OFF_XT);
  float* w_sq    = (float*)(ws + OFF_SQ);
  float* w_den   = (float*)(ws + OFF_DEN);
  float* w_score = (float*)(ws + OFF_SCORE);
  float* w_wt    = (float*)(ws + OFF_WT);
  float* w_awd   = (float*)(ws + OFF_AWD);
  int*   w_idxd  = (int*)  (ws + OFF_IDXD);
  int*   w_idxc  = (int*)  (ws + OFF_IDXC);
  int*   w_inv   = (int*)  (ws + OFF_INV);
  float* w_wtr   = (float*)(ws + OFF_WTR);
  float* w_swt   = (float*)(ws + OFF_SWT);
  float* w_p     = (float*)(ws + OFF_P);
  u16*   w_xh    = (u16*)  (ws + OFF_XH);
  u16*   w_xm    = (u16*)  (ws + OFF_XM);
  u16*   w_xl    = (u16*)  (ws + OFF_XL);
  float* w_dpart = (float*)(ws + OFF_P);    // aliases P (dead after conv_gemm)
  float* w_ppart = (float*)(ws + OFF_PP);
  float* w_apd   = (float*)(ws + OFF_APD);
  int*   w_apm   = (int*)  (ws + OFF_APM);

  float* out0 = (float*)d_out;
  float* out1 = out0 + NB*MC*DOUT;
  float* out2 = out1 + NB*NT;

  hipMemsetAsync(ws, 0, ZERO_BYTES, stream);
  hipMemsetAsync(out0, 0, (size_t)NB*MC*DOUT*sizeof(float), stream);

  t2m_scatter<<<NB*NT*CI/256, 256, 0, stream>>>(x, loc, idxagg, aggw, w_xmap, w_cnt, w_tot);
  wprep_kernel<<<1280, 256, 0, stream>>>(convw, skipw, w_wtr, w_swt);
  im2col_kernel<<<2048, 256, 0, stream>>>(w_xmap, w_cnt, w_p);
  conv_gemm<<<dim3(64, 8), 256, 0, stream>>>(w_p, w_wtr, convb, w_ymap);
  skip_kernel<<<NB*NT/8, 256, 0, stream>>>(x, w_swt, w_xt);
  m2t_scatter<<<NB*NT, 256, 0, stream>>>(w_ymap, loc, idxagg, aggw, w_tot, w_xt);
  ln_kernel<<<NB*NT, 256, 0, stream>>>(w_xt, lng, lnb, confw, confb, w_sq, w_wt);
  xsplit_kernel<<<NB*NT*DOUT/512, 256, 0, stream>>>(w_xt, w_xh, w_xm, w_xl);

  dens_mfma   <<<dim3(528, NB), 256, 0, stream>>>(w_xh, w_xm, w_xl, w_sq, w_dpart);
  dens_merge  <<<dim3(16, NB), 256, 0, stream>>>(w_dpart, w_den, w_vmax);
  parent_mfma <<<dim3(528, NB), 256, 0, stream>>>(w_xh, w_xm, w_xl, w_sq, w_den, w_ppart);
  parent_merge<<<dim3(16, NB), 256, 0, stream>>>(w_ppart, w_den, w_vmax, w_score);
  topk_all    <<<NB, 1024, 0, stream>>>(w_score, w_idxd, w_inv);
  assign_mfma <<<dim3(256, NB), 256, 0, stream>>>(w_xh, w_xm, w_xl, w_sq, w_idxd, w_apd, w_apm);
  assign_merge<<<dim3(16, NB), 256, 0, stream>>>(w_apd, w_apm, w_inv, w_wt, w_idxc, w_allw);

  xdown_kernel<<<NB*NT, 256, 0, stream>>>(w_idxc, w_wt, w_allw, w_xt, out0);
  out12a_kernel<<<NB*NT/256, 256, 0, stream>>>(idxagg, w_idxc, aggw, w_wt, w_allw, w_awd, w_awdm, out1);
  out2_kernel<<<NB*NT/256, 256, 0, stream>>>(w_awd, w_awdm, out2);

  (void)in_sizes; (void)n_in; (void)out_size; (void)ws_size;
}

// Round 12
// 687.977 us; speedup vs baseline: 1.0065x; 1.0065x over previous
//
#include <hip/hip_runtime.h>
#include <math.h>

// B=4, N=4096, C=128, DOUT=256, H=W=64 (conv out 32x32), M=1024, K=5.
#define NB 4
#define NT 4096
#define CI 128
#define DOUT 256
#define HWI 4096
#define HWO 1024
#define MC 1024
#define EPS_F 1e-6f

typedef unsigned short u16;
typedef __attribute__((ext_vector_type(8))) short bf16x8;
typedef __attribute__((ext_vector_type(4))) float f32x4;

// ---------------- workspace layout (bytes) ----------------
// zero zone:
static const size_t OFF_XMAP  = 0;                          // 8388608
static const size_t OFF_CNT   = OFF_XMAP + 8388608;         // 65536
static const size_t OFF_TOT   = OFF_CNT  + 65536;           // 65536
static const size_t OFF_ALLW  = OFF_TOT  + 65536;           // 16384
static const size_t OFF_VMAX  = OFF_ALLW + 16384;           // 256
static const size_t OFF_AWDM  = OFF_VMAX + 256;             // 256
static const size_t ZERO_BYTES= OFF_AWDM + 256;
// non-zeroed:
static const size_t OFF_YMAP  = ZERO_BYTES;                 // 4194304
static const size_t OFF_XT    = OFF_YMAP + 4194304;         // 16777216
static const size_t OFF_SQ    = OFF_XT + 16777216;          // 65536
static const size_t OFF_DEN   = OFF_SQ + 65536;
static const size_t OFF_SCORE = OFF_DEN + 65536;
static const size_t OFF_WT    = OFF_SCORE + 65536;
static const size_t OFF_AWD   = OFF_WT + 65536;
static const size_t OFF_IDXD  = OFF_AWD + 65536;            // 16384
static const size_t OFF_IDXC  = OFF_IDXD + 16384;           // 65536
static const size_t OFF_INV   = OFF_IDXC + 65536;           // 65536 (init in topk)
static const size_t OFF_WTR   = OFF_INV + 65536;            // 1179648 (wT[1152][256])
static const size_t OFF_SWT   = OFF_WTR + 1179648;          // 131072 (swT[128][256])
static const size_t OFF_P     = OFF_SWT + 131072;           // 18874368 (P dead after conv -> Dpart aliases)
static const size_t OFF_XH    = OFF_P + 18874368;           // 8388608 (bf16 hi)
static const size_t OFF_XM    = OFF_XH + 8388608;           // 8388608 (bf16 mid)
static const size_t OFF_XL    = OFF_XM + 8388608;           // 8388608 (bf16 lo)
// G eliminated. Cluster buffers:
static const size_t OFF_PP    = OFF_XL + 8388608;              // Ppart: NB*NT*32*4 = 2MB
static const size_t OFF_APD   = OFF_PP + (size_t)NB*NT*32*4;   // NB*NT*8*4 = 512KB
static const size_t OFF_APM   = OFF_APD + (size_t)NB*NT*8*4;   // 512KB
// dense gathered centers (r12): [b][MC][256] bf16 per comp + sqc[b][MC]
static const size_t OFF_XCH   = OFF_APM + (size_t)NB*NT*8*4;   // 2MB
static const size_t OFF_XCM   = OFF_XCH + (size_t)NB*MC*256*2; // 2MB
static const size_t OFF_XCL   = OFF_XCM + (size_t)NB*MC*256*2; // 2MB
static const size_t OFF_SQC   = OFF_XCL + (size_t)NB*MC*256*2; // 16KB
// Dpart: [b][4096 rows][32 tiles][6] floats = 3MB/slice x4, aliases OFF_P.
static const size_t DPSTRIDE  = (size_t)NT*32*6;            // floats per slice
static const size_t PPSTRIDE  = (size_t)NT*32;              // floats per slice

// ---------------- helpers ----------------
__device__ __forceinline__ float waveSum(float v){
#pragma unroll
  for (int m = 1; m < 64; m <<= 1) v += __shfl_xor(v, m, 64);
  return v;
}
__device__ __forceinline__ float blockSum256(float v, float* red){
  v = waveSum(v);
  int lane = threadIdx.x & 63, wid = threadIdx.x >> 6;
  __syncthreads();
  if (lane == 0) red[wid] = v;
  __syncthreads();
  return red[0] + red[1] + red[2] + red[3];
}
__device__ __forceinline__ void merge5(float& a0, float& a1, float& a2, float& a3, float& a4,
                                       float b0, float b1, float b2, float b3, float b4){
  float l0=a0,l1=a1,l2=a2,l3=fminf(a3,b4),l4=fminf(a4,b3),l5=b2,l6=b1,l7=b0;
  float t0=fminf(l0,l4), t4=fmaxf(l0,l4);
  float t1=fminf(l1,l5), t5=fmaxf(l1,l5);
  float t2=fminf(l2,l6), t6=fmaxf(l2,l6);
  float t3=fminf(l3,l7), t7=fmaxf(l3,l7);
  float u0=fminf(t0,t2), u2=fmaxf(t0,t2);
  float u1=fminf(t1,t3), u3=fmaxf(t1,t3);
  float u4=fminf(t4,t6);
  float u5=fminf(t5,t7);
  a0=fminf(u0,u1); a1=fmaxf(u0,u1);
  a2=fminf(u2,u3); a3=fmaxf(u2,u3);
  a4=fminf(u4,u5);
}
__device__ __forceinline__ void ins5(float v, float& t0, float& t1, float& t2, float& t3, float& t4){
  t4 = fminf(t4, v);
  float a;
  a = fminf(t3,t4); t4 = fmaxf(t3,t4); t3 = a;
  a = fminf(t2,t3); t3 = fmaxf(t2,t3); t2 = a;
  a = fminf(t1,t2); t2 = fmaxf(t1,t2); t1 = a;
  a = fminf(t0,t1); t1 = fmaxf(t0,t1); t0 = a;
}
__device__ __forceinline__ int grid_cell(float lx, float ly, int dim){
  lx = (fminf(fmaxf(lx, -1.f), 1.f) + 1.f) * 0.5f;
  ly = (fminf(fmaxf(ly, -1.f), 1.f) + 1.f) * 0.5f;
  float s = (float)(dim - 1);
  int col = (int)rintf(lx * s); col = min(max(col, 0), dim - 1);
  int row = (int)rintf(ly * s); row = min(max(row, 0), dim - 1);
  return row * dim + col;
}

// ---------------- front-end kernels ----------------
__global__ __launch_bounds__(256) void t2m_scatter(const float* __restrict__ x,
                                                   const float* __restrict__ loc,
                                                   const int* __restrict__ idx_agg,
                                                   const float* __restrict__ aggw,
                                                   float* __restrict__ xmap, float* __restrict__ cnt,
                                                   float* __restrict__ tot){
  int lin = blockIdx.x * 256 + threadIdx.x;
  int c  = lin & 127;
  int bn = lin >> 7;
  int b  = bn >> 12;
  float lx = loc[(size_t)bn*2 + 0];
  float ly = loc[(size_t)bn*2 + 1];
  int cell = grid_cell(lx, ly, 64);
  int ia = idx_agg[bn];
  float val = x[((size_t)(b*NT + ia))*CI + c];
  atomicAdd(&xmap[((size_t)(b*HWI + cell))*CI + c], val);
  if (c == 0) atomicAdd(&cnt[b*HWI + cell], 1.0f);
  if (c == 1) atomicAdd(&tot[b*NT + ia], aggw[bn]);
}

// fused weight prep: wT[k][d] = conv_w[d][k]; swT[c][d] = skip_w[d][c]
__global__ __launch_bounds__(256) void wprep_kernel(const float* __restrict__ cw, const float* __restrict__ sw,
                                                    float* __restrict__ wT, float* __restrict__ swT){
  int lin = blockIdx.x * 256 + threadIdx.x;
  if (lin < 1152*256){
    int k = lin >> 8, d = lin & 255;
    wT[lin] = cw[(size_t)d*1152 + k];
  } else {
    int i = lin - 1152*256;
    int c = i >> 8, d = i & 255;
    swT[i] = sw[d*128 + c];
  }
}

__global__ __launch_bounds__(256) void im2col_kernel(const float* __restrict__ xmap,
                                                     const float* __restrict__ cnt,
                                                     float* __restrict__ P){
  int tid = threadIdx.x;
  int c = tid & 127, n2 = tid >> 7;
  int n = blockIdx.x * 2 + n2;
  int b = n >> 10, rem = n & 1023;
  int oh = rem >> 5, ow = rem & 31;
  const float* xb = xmap + (size_t)b*HWI*CI;
  const float* cb_ = cnt + (size_t)b*HWI;
  float* prow = P + (size_t)n*1152 + c*9;
#pragma unroll
  for (int kh = 0; kh < 3; ++kh){
    int ih = oh*2 - 1 + kh;
#pragma unroll
    for (int kw = 0; kw < 3; ++kw){
      int iw = ow*2 - 1 + kw;
      bool inb = (ih >= 0) && (ih < 64) && (iw >= 0) && (iw < 64);
      float v = 0.f;
      if (inb){
        int cell = ih*64 + iw;
        v = xb[(size_t)cell*CI + c] / (cb_[cell] + EPS_F);
      }
      prow[kh*3 + kw] = v;
    }
  }
}

// conv GEMM: 64(n) x 32(d) tiles. Grid (64 n0, 8 d0) for A-panel L2 locality.
__global__ __launch_bounds__(256) void conv_gemm(const float* __restrict__ P,
                                                 const float* __restrict__ wT,
                                                 const float* __restrict__ cb,
                                                 float* __restrict__ ymap){
  __shared__ float As[16][64];
  __shared__ float Bs[16][32];
  int n0 = blockIdx.x * 64, d0 = blockIdx.y * 32;
  int tid = threadIdx.x;
  int tx = tid & 15, ty = tid >> 4;
  int ln = tid & 63, kq = tid >> 6;
  int bkr = tid >> 3, bc4 = (tid & 7) * 4;
  float4 pav = *(const float4*)(P + (size_t)(n0+ln)*1152 + kq*4);
  float4 pbv;
  if (tid < 128) pbv = *(const float4*)(wT + (size_t)bkr*256 + d0 + bc4);
  float acc[4][2] = {{0}};
  for (int kt = 0; kt < 72; ++kt){
    __syncthreads();
    As[kq*4+0][ln]=pav.x; As[kq*4+1][ln]=pav.y; As[kq*4+2][ln]=pav.z; As[kq*4+3][ln]=pav.w;
    if (tid < 128) *(float4*)&Bs[bkr][bc4] = pbv;
    __syncthreads();
    if (kt < 71){
      int k2 = (kt + 1) * 16;
      pav = *(const float4*)(P + (size_t)(n0+ln)*1152 + k2 + kq*4);
      if (tid < 128) pbv = *(const float4*)(wT + (size_t)(k2 + bkr)*256 + d0 + bc4);
    }
#pragma unroll
    for (int k = 0; k < 16; ++k){
      float ar[4];
      *(float4*)ar = *(const float4*)&As[k][ty*4];
      float b0 = Bs[k][tx*2], b1 = Bs[k][tx*2+1];
#pragma unroll
      for (int r = 0; r < 4; ++r){ acc[r][0] += ar[r]*b0; acc[r][1] += ar[r]*b1; }
    }
  }
  float c0 = cb[d0 + tx*2], c1 = cb[d0 + tx*2 + 1];
#pragma unroll
  for (int r = 0; r < 4; ++r){
    float2 o; o.x = acc[r][0] + c0; o.y = acc[r][1] + c1;
    *(float2*)(ymap + (size_t)(n0 + ty*4 + r)*DOUT + d0 + tx*2) = o;
  }
}

// xt = x @ skip_w.T via transposed weights (coalesced); c ascending -> bit-identical
__global__ __launch_bounds__(256) void skip_kernel(const float* __restrict__ x,
                                                   const float* __restrict__ swT,
                                                   float* __restrict__ xt){
  int rowbase = blockIdx.x * 8;
  int d = threadIdx.x;
  __shared__ float xr[8*128];
  ((float4*)xr)[d] = ((const float4*)(x + (size_t)rowbase*CI))[d];
  __syncthreads();
  float acc[8] = {0,0,0,0,0,0,0,0};
  for (int c = 0; c < 128; ++c){
    float w = swT[c*256 + d];
#pragma unroll
    for (int r = 0; r < 8; ++r) acc[r] += w * xr[r*128 + c];
  }
  for (int r = 0; r < 8; ++r) xt[(size_t)(rowbase + r)*DOUT + d] = acc[r];
}

__global__ __launch_bounds__(256) void m2t_scatter(const float* __restrict__ ymap,
                                                   const float* __restrict__ loc,
                                                   const int* __restrict__ idx_agg,
                                                   const float* __restrict__ aggw,
                                                   const float* __restrict__ tot,
                                                   float* __restrict__ xt){
  int bn = blockIdx.x;
  int d = threadIdx.x;
  int b = bn >> 12;
  float lx = loc[(size_t)bn*2 + 0];
  float ly = loc[(size_t)bn*2 + 1];
  int cell = grid_cell(lx, ly, 32);
  int ia = idx_agg[bn];
  float w = aggw[bn] / (tot[b*NT + ia] + EPS_F);
  float val = ymap[((size_t)(b*HWO + cell))*DOUT + d] * w;
  atomicAdd(&xt[((size_t)(b*NT + ia))*DOUT + d], val);
}

__global__ __launch_bounds__(256) void ln_kernel(float* __restrict__ xt,
                                                 const float* __restrict__ g,
                                                 const float* __restrict__ bta,
                                                 const float* __restrict__ cw,
                                                 const float* __restrict__ cb,
                                                 float* __restrict__ sq, float* __restrict__ wt){
  __shared__ float red[4];
  int row = blockIdx.x;
  int d = threadIdx.x;
  float v = xt[(size_t)row*DOUT + d];
  float mu = blockSum256(v, red) * (1.0f/256.0f);
  float xc = v - mu;
  float var = blockSum256(xc*xc, red) * (1.0f/256.0f);
  float rn = 1.0f / sqrtf(var + 1e-5f);
  float y = xc * rn * g[d] + bta[d];
  xt[(size_t)row*DOUT + d] = y;
  float s2 = blockSum256(y*y, red);
  float cf = blockSum256(y*cw[d], red);
  if (d == 0){ sq[row] = s2; wt[row] = expf(cf + cb[0]); }
}

// xsplit: exact 3-way bf16 truncation split xt = hi + mid + lo (24 mantissa bits).
__global__ __launch_bounds__(256) void xsplit_kernel(const float* __restrict__ xt,
                                                     u16* __restrict__ xh,
                                                     u16* __restrict__ xm,
                                                     u16* __restrict__ xl){
  int idx = blockIdx.x*256 + threadIdx.x;
  float2 v = *(const float2*)(xt + (size_t)idx*2);
  unsigned ph, pm, pl;
  {
    unsigned u = __float_as_uint(v.x);
    unsigned h0 = u >> 16;
    float r1 = v.x - __uint_as_float(u & 0xFFFF0000u);
    unsigned u1 = __float_as_uint(r1);
    unsigned m0 = u1 >> 16;
    float r2 = r1 - __uint_as_float(u1 & 0xFFFF0000u);
    unsigned l0 = __float_as_uint(r2) >> 16;
    unsigned u2 = __float_as_uint(v.y);
    unsigned h1 = u2 >> 16;
    float s1 = v.y - __uint_as_float(u2 & 0xFFFF0000u);
    unsigned u3 = __float_as_uint(s1);
    unsigned m1 = u3 >> 16;
    float s2 = s1 - __uint_as_float(u3 & 0xFFFF0000u);
    unsigned l1 = __float_as_uint(s2) >> 16;
    ph = h0 | (h1 << 16); pm = m0 | (m1 << 16); pl = l0 | (l1 << 16);
  }
  *(unsigned*)(xh + (size_t)idx*2) = ph;
  *(unsigned*)(xm + (size_t)idx*2) = pm;
  *(unsigned*)(xl + (size_t)idx*2) = pl;
}

// ---------------- clustering (G never materialized) ----------------
// dens_mfma: bf16x3 MFMA tiles (6 cross terms, fp32 accum); density partials
// only. Identical arithmetic to r10/r11 -> density/vmax bit-identical.
__global__ __launch_bounds__(256) void dens_mfma(const u16* __restrict__ xh,
                                                 const u16* __restrict__ xm,
                                                 const u16* __restrict__ xl,
                                                 const float* __restrict__ sq,
                                                 float* __restrict__ Dpart){
  __shared__ u16 usmem[24576];
  u16* Au = usmem;
  u16* Bu = usmem + 12288;
  int b = blockIdx.y;
  float* Dp = Dpart + (size_t)b*DPSTRIDE;
  int t = blockIdx.x;
  int ti = 0, accu = 0;
  while (accu + ti + 1 <= t){ accu += ti + 1; ++ti; }
  int tj = t - accu;
  int i0 = ti*128, j0 = tj*128;
  int tid = threadIdx.x;
  int w = tid >> 6, l = tid & 63;
  int lrow = l & 15, lg = l >> 4;
  int li = tid & 127, kq = tid >> 7;
  const size_t base = (size_t)b*NT*256;
  size_t arow = base + (size_t)(i0 + li)*256 + kq*16;
  size_t brow = base + (size_t)(j0 + li)*256 + kq*16;
  const u16* csrc[3] = {xh, xm, xl};
  int ga0 = ((li*4 + kq*2 + 0) ^ (li & 7)) * 8;
  int ga1 = ((li*4 + kq*2 + 1) ^ (li & 7)) * 8;
  f32x4 acc[2][8];
  f32x4 z; z[0]=0.f; z[1]=0.f; z[2]=0.f; z[3]=0.f;
#pragma unroll
  for (int mr = 0; mr < 2; ++mr)
#pragma unroll
    for (int n0 = 0; n0 < 8; ++n0) acc[mr][n0] = z;
  for (int kc = 0; kc < 8; ++kc){
    int k0 = kc*32;
    __syncthreads();
#pragma unroll
    for (int c = 0; c < 3; ++c){
      const u16* s = csrc[c];
      bf16x8 a0 = *(const bf16x8*)(s + arow + k0);
      bf16x8 a1 = *(const bf16x8*)(s + arow + k0 + 8);
      bf16x8 b0 = *(const bf16x8*)(s + brow + k0);
      bf16x8 b1 = *(const bf16x8*)(s + brow + k0 + 8);
      *(bf16x8*)(Au + c*4096 + ga0) = a0;
      *(bf16x8*)(Au + c*4096 + ga1) = a1;
      *(bf16x8*)(Bu + c*4096 + ga0) = b0;
      *(bf16x8*)(Bu + c*4096 + ga1) = b1;
    }
    __syncthreads();
    bf16x8 af[2][3];
#pragma unroll
    for (int mr = 0; mr < 2; ++mr){
      int row = w*32 + mr*16 + lrow;
      int off = ((row*4 + lg) ^ (row & 7)) * 8;
#pragma unroll
      for (int c = 0; c < 3; ++c)
        af[mr][c] = *(const bf16x8*)(Au + c*4096 + off);
    }
#pragma unroll
    for (int n0 = 0; n0 < 8; ++n0){
      int rowb = n0*16 + lrow;
      int offb = ((rowb*4 + lg) ^ (rowb & 7)) * 8;
      bf16x8 bh = *(const bf16x8*)(Bu + 0*4096 + offb);
      bf16x8 bm = *(const bf16x8*)(Bu + 1*4096 + offb);
      bf16x8 bl = *(const bf16x8*)(Bu + 2*4096 + offb);
#pragma unroll
      for (int mr = 0; mr < 2; ++mr){
        acc[mr][n0] = __builtin_amdgcn_mfma_f32_16x16x32_bf16(af[mr][0], bh, acc[mr][n0], 0, 0, 0);
        acc[mr][n0] = __builtin_amdgcn_mfma_f32_16x16x32_bf16(af[mr][0], bm, acc[mr][n0], 0, 0, 0);
        acc[mr][n0] = __builtin_amdgcn_mfma_f32_16x16x32_bf16(af[mr][1], bh, acc[mr][n0], 0, 0, 0);
        acc[mr][n0] = __builtin_amdgcn_mfma_f32_16x16x32_bf16(af[mr][1], bm, acc[mr][n0], 0, 0, 0);
        acc[mr][n0] = __builtin_amdgcn_mfma_f32_16x16x32_bf16(af[mr][0], bl, acc[mr][n0], 0, 0, 0);
        acc[mr][n0] = __builtin_amdgcn_mfma_f32_16x16x32_bf16(af[mr][2], bh, acc[mr][n0], 0, 0, 0);
      }
    }
  }
  const float* sqb2 = sq + b*NT;
  // i-side density partials
  {
    float sqj_c[8];
#pragma unroll
    for (int n0 = 0; n0 < 8; ++n0) sqj_c[n0] = sqb2[j0 + n0*16 + lrow];
#pragma unroll
    for (int mr = 0; mr < 2; ++mr)
#pragma unroll
      for (int r = 0; r < 4; ++r){
        int row = i0 + w*32 + mr*16 + lg*4 + r;
        float sqi_v = sqb2[row];
        float t0=INFINITY,t1=INFINITY,t2=INFINITY,t3=INFINITY,t4=INFINITY;
        float mx = 0.f;
#pragma unroll
        for (int n0 = 0; n0 < 8; ++n0){
          float v = fmaxf(sqi_v + sqj_c[n0] - 2.0f*acc[mr][n0][r], 0.0f);
          mx = fmaxf(mx, v);
          ins5(v,t0,t1,t2,t3,t4);
        }
#pragma unroll
        for (int m = 1; m < 16; m <<= 1){
          float b0=__shfl_xor(t0,m,64), b1=__shfl_xor(t1,m,64), b2=__shfl_xor(t2,m,64),
                b3=__shfl_xor(t3,m,64), b4=__shfl_xor(t4,m,64);
          merge5(t0,t1,t2,t3,t4,b0,b1,b2,b3,b4);
          mx = fmaxf(mx, __shfl_xor(mx,m,64));
        }
        if (lrow == 0){
          float* dpp = Dp + ((size_t)row*32 + tj)*6;
          dpp[0]=t0; dpp[1]=t1; dpp[2]=t2; dpp[3]=t3; dpp[4]=t4; dpp[5]=mx;
        }
      }
  }
  if (ti != tj){
    // j-side partials via LDS transpose chunks
    float* T = (float*)usmem;
    int q = tid >> 3, u = tid & 7;
    float sqi_u[16];
#pragma unroll
    for (int e = 0; e < 16; ++e) sqi_u[e] = sqb2[i0 + u*16 + e];
#pragma unroll
    for (int cc = 0; cc < 4; ++cc){
      __syncthreads();
#pragma unroll
      for (int nn = 0; nn < 2; ++nn){
        int n0 = cc*2 + nn;
#pragma unroll
        for (int mr = 0; mr < 2; ++mr)
#pragma unroll
          for (int r = 0; r < 4; ++r)
            T[(nn*16 + lrow)*129 + w*32 + mr*16 + lg*4 + r] = acc[mr][n0][r];
      }
      __syncthreads();
      const float* Trow = &T[q*129 + u*16];
      float gv[16];
#pragma unroll
      for (int e = 0; e < 16; ++e) gv[e] = Trow[e];
      int jr = j0 + cc*32 + q;
      float sqj_m = sqb2[jr];
      float t0=INFINITY,t1=INFINITY,t2=INFINITY,t3=INFINITY,t4=INFINITY;
      float mx = 0.f;
#pragma unroll
      for (int e = 0; e < 16; ++e){
        float v = fmaxf(sqj_m + sqi_u[e] - 2.0f*gv[e], 0.0f);
        mx = fmaxf(mx, v);
        ins5(v,t0,t1,t2,t3,t4);
      }
#pragma unroll
      for (int m = 1; m < 8; m <<= 1){
        float b0=__shfl_xor(t0,m,64), b1=__shfl_xor(t1,m,64), b2=__shfl_xor(t2,m,64),
              b3=__shfl_xor(t3,m,64), b4=__shfl_xor(t4,m,64);
        merge5(t0,t1,t2,t3,t4,b0,b1,b2,b3,b4);
        mx = fmaxf(mx, __shfl_xor(mx,m,64));
      }
      if (u == 0){
        float* dpp = Dp + ((size_t)jr*32 + ti)*6;
        dpp[0]=t0; dpp[1]=t1; dpp[2]=t2; dpp[3]=t3; dpp[4]=t4; dpp[5]=mx;
      }
    }
  }
}

// dens_merge: fold 32 sorted per-tile partials per row -> density + vmax (exact).
__global__ __launch_bounds__(256) void dens_merge(const float* __restrict__ Dpart,
                                                  float* __restrict__ density, int* __restrict__ vmax){
  int b = blockIdx.y;
  const float* Dp = Dpart + (size_t)b*DPSTRIDE;
  int row = blockIdx.x*256 + threadIdx.x;
  const float* p = Dp + (size_t)row*32*6;
  float t0=INFINITY,t1=INFINITY,t2=INFINITY,t3=INFINITY,t4=INFINITY;
  float mx = 0.f;
#pragma unroll 4
  for (int tt = 0; tt < 32; ++tt){
    merge5(t0,t1,t2,t3,t4, p[tt*6+0], p[tt*6+1], p[tt*6+2], p[tt*6+3], p[tt*6+4]);
    mx = fmaxf(mx, p[tt*6+5]);
  }
  float d0=sqrtf(t0)*0.0625f, d1=sqrtf(t1)*0.0625f, d2=sqrtf(t2)*0.0625f,
        d3=sqrtf(t3)*0.0625f, d4=sqrtf(t4)*0.0625f;
  float s = d0*d0; s += d1*d1; s += d2*d2; s += d3*d3; s += d4*d4;
  density[b*NT + row] = expf(-(s / 5.0f));
#pragma unroll
  for (int m = 1; m < 64; m <<= 1) mx = fmaxf(mx, __shfl_xor(mx, m, 64));
  if ((threadIdx.x & 63) == 0) atomicMax(vmax + b, __float_as_int(mx));
}

// parent_mfma: second tile pass; per-row min over candidates with den>di.
// acc values identical to dens_mfma; fmin exact -> score bit-identical.
__global__ __launch_bounds__(256) void parent_mfma(const u16* __restrict__ xh,
                                                   const u16* __restrict__ xm,
                                                   const u16* __restrict__ xl,
                                                   const float* __restrict__ sq,
                                                   const float* __restrict__ den,
                                                   float* __restrict__ Ppart){
  __shared__ u16 usmem[24576];
  u16* Au = usmem;
  u16* Bu = usmem + 12288;
  int b = blockIdx.y;
  float* Pp = Ppart + (size_t)b*PPSTRIDE;
  int t = blockIdx.x;
  int ti = 0, accu = 0;
  while (accu + ti + 1 <= t){ accu += ti + 1; ++ti; }
  int tj = t - accu;
  int i0 = ti*128, j0 = tj*128;
  int tid = threadIdx.x;
  int w = tid >> 6, l = tid & 63;
  int lrow = l & 15, lg = l >> 4;
  int li = tid & 127, kq = tid >> 7;
  const size_t base = (size_t)b*NT*256;
  size_t arow = base + (size_t)(i0 + li)*256 + kq*16;
  size_t brow = base + (size_t)(j0 + li)*256 + kq*16;
  const u16* csrc[3] = {xh, xm, xl};
  int ga0 = ((li*4 + kq*2 + 0) ^ (li & 7)) * 8;
  int ga1 = ((li*4 + kq*2 + 1) ^ (li & 7)) * 8;
  f32x4 acc[2][8];
  f32x4 z; z[0]=0.f; z[1]=0.f; z[2]=0.f; z[3]=0.f;
#pragma unroll
  for (int mr = 0; mr < 2; ++mr)
#pragma unroll
    for (int n0 = 0; n0 < 8; ++n0) acc[mr][n0] = z;
  for (int kc = 0; kc < 8; ++kc){
    int k0 = kc*32;
    __syncthreads();
#pragma unroll
    for (int c = 0; c < 3; ++c){
      const u16* s = csrc[c];
      bf16x8 a0 = *(const bf16x8*)(s + arow + k0);
      bf16x8 a1 = *(const bf16x8*)(s + arow + k0 + 8);
      bf16x8 b0 = *(const bf16x8*)(s + brow + k0);
      bf16x8 b1 = *(const bf16x8*)(s + brow + k0 + 8);
      *(bf16x8*)(Au + c*4096 + ga0) = a0;
      *(bf16x8*)(Au + c*4096 + ga1) = a1;
      *(bf16x8*)(Bu + c*4096 + ga0) = b0;
      *(bf16x8*)(Bu + c*4096 + ga1) = b1;
    }
    __syncthreads();
    bf16x8 af[2][3];
#pragma unroll
    for (int mr = 0; mr < 2; ++mr){
      int row = w*32 + mr*16 + lrow;
      int off = ((row*4 + lg) ^ (row & 7)) * 8;
#pragma unroll
      for (int c = 0; c < 3; ++c)
        af[mr][c] = *(const bf16x8*)(Au + c*4096 + off);
    }
#pragma unroll
    for (int n0 = 0; n0 < 8; ++n0){
      int rowb = n0*16 + lrow;
      int offb = ((rowb*4 + lg) ^ (rowb & 7)) * 8;
      bf16x8 bh = *(const bf16x8*)(Bu + 0*4096 + offb);
      bf16x8 bm = *(const bf16x8*)(Bu + 1*4096 + offb);
      bf16x8 bl = *(const bf16x8*)(Bu + 2*4096 + offb);
#pragma unroll
      for (int mr = 0; mr < 2; ++mr){
        acc[mr][n0] = __builtin_amdgcn_mfma_f32_16x16x32_bf16(af[mr][0], bh, acc[mr][n0], 0, 0, 0);
        acc[mr][n0] = __builtin_amdgcn_mfma_f32_16x16x32_bf16(af[mr][0], bm, acc[mr][n0], 0, 0, 0);
        acc[mr][n0] = __builtin_amdgcn_mfma_f32_16x16x32_bf16(af[mr][1], bh, acc[mr][n0], 0, 0, 0);
        acc[mr][n0] = __builtin_amdgcn_mfma_f32_16x16x32_bf16(af[mr][1], bm, acc[mr][n0], 0, 0, 0);
        acc[mr][n0] = __builtin_amdgcn_mfma_f32_16x16x32_bf16(af[mr][0], bl, acc[mr][n0], 0, 0, 0);
        acc[mr][n0] = __builtin_amdgcn_mfma_f32_16x16x32_bf16(af[mr][2], bh, acc[mr][n0], 0, 0, 0);
      }
    }
  }
  const float* sqb2 = sq + b*NT;
  const float* denb = den + b*NT;
  // i-side: rows in ti-block, candidates = tj-block cols
  {
    float sqj_c[8], dnj_c[8];
#pragma unroll
    for (int n0 = 0; n0 < 8; ++n0){
      sqj_c[n0] = sqb2[j0 + n0*16 + lrow];
      dnj_c[n0] = denb[j0 + n0*16 + lrow];
    }
#pragma unroll
    for (int mr = 0; mr < 2; ++mr)
#pragma unroll
      for (int r = 0; r < 4; ++r){
        int row = i0 + w*32 + mr*16 + lg*4 + r;
        float di = denb[row];
        float sqi_v = sqb2[row];
        float mn = INFINITY;
#pragma unroll
        for (int n0 = 0; n0 < 8; ++n0){
          float v = fmaxf(sqi_v + sqj_c[n0] - 2.0f*acc[mr][n0][r], 0.0f);
          mn = fminf(mn, (dnj_c[n0] > di) ? v : INFINITY);
        }
#pragma unroll
        for (int m = 1; m < 16; m <<= 1) mn = fminf(mn, __shfl_xor(mn, m, 64));
        if (lrow == 0) Pp[(size_t)row*32 + tj] = mn;
      }
  }
  if (ti != tj){
    float* T = (float*)usmem;
    int q = tid >> 3, u = tid & 7;
    float sqi_u[16], dni_u[16];
#pragma unroll
    for (int e = 0; e < 16; ++e){
      sqi_u[e] = sqb2[i0 + u*16 + e];
      dni_u[e] = denb[i0 + u*16 + e];
    }
#pragma unroll
    for (int cc = 0; cc < 4; ++cc){
      __syncthreads();
#pragma unroll
      for (int nn = 0; nn < 2; ++nn){
        int n0 = cc*2 + nn;
#pragma unroll
        for (int mr = 0; mr < 2; ++mr)
#pragma unroll
          for (int r = 0; r < 4; ++r)
            T[(nn*16 + lrow)*129 + w*32 + mr*16 + lg*4 + r] = acc[mr][n0][r];
      }
      __syncthreads();
      const float* Trow = &T[q*129 + u*16];
      int jr = j0 + cc*32 + q;
      float dj = denb[jr];
      float sqj_m = sqb2[jr];
      float mn = INFINITY;
#pragma unroll
      for (int e = 0; e < 16; ++e){
        float v = fmaxf(sqj_m + sqi_u[e] - 2.0f*Trow[e], 0.0f);
        mn = fminf(mn, (dni_u[e] > dj) ? v : INFINITY);
      }
#pragma unroll
      for (int m = 1; m < 8; m <<= 1) mn = fminf(mn, __shfl_xor(mn, m, 64));
      if (u == 0) Pp[(size_t)jr*32 + ti] = mn;
    }
  }
}

// parent_merge: fold 32 partial mins per row -> score.
__global__ __launch_bounds__(256) void parent_merge(const float* __restrict__ Ppart,
                                                    const float* __restrict__ density,
                                                    const int* __restrict__ vmax,
                                                    float* __restrict__ score){
  int b = blockIdx.y;
  int row = blockIdx.x*256 + threadIdx.x;
  const float* p = Ppart + (size_t)b*PPSTRIDE + (size_t)row*32;
  float mn = INFINITY;
#pragma unroll 4
  for (int tt = 0; tt < 32; ++tt) mn = fminf(mn, p[tt]);
  float dmax = sqrtf(__int_as_float(vmax[b])) * 0.0625f;
  float dp = isinf(mn) ? dmax : sqrtf(mn) * 0.0625f;
  score[b*NT + row] = dp * density[b*NT + row];
}

// ---------------- topk: hybrid bitonic sort 4096 (score desc, idx asc) ----------------
__device__ __forceinline__ bool kv_lt(float s1, int a1, float s2, int a2){
  return (s1 > s2) || (s1 == s2 && a1 < a2);
}
#define KV_CMPX(sx,ax,sy,ay,up) do{ bool _l = kv_lt(sx,ax,sy,ay); \
  if (_l != (up)) { float _ts=sx; sx=sy; sy=_ts; int _ta=ax; ax=ay; ay=_ta; } }while(0)
#define KV_TAKE(sx,ax,ps,pa,eqd) do{ bool _keep = kv_lt(sx,ax,ps,pa) == (eqd); \
  if(!_keep){ sx=(ps); ax=(pa); } }while(0)

__global__ __launch_bounds__(1024) void topk_all(const float* __restrict__ score, int* __restrict__ idx_down,
                                                 int* __restrict__ inv){
  __shared__ float ss[4096];
  __shared__ int ii[4096];
  int b = blockIdx.x;
  int t = threadIdx.x;
  float s0,s1,s2,s3; int a0,a1,a2,a3;
  {
    float4 v = *(const float4*)(score + b*NT + 4*t);
    s0=v.x; s1=v.y; s2=v.z; s3=v.w;
    a0=4*t; a1=4*t+1; a2=4*t+2; a3=4*t+3;
    int4 mi; mi.x=-1; mi.y=-1; mi.z=-1; mi.w=-1;
    *(int4*)(inv + b*NT + 4*t) = mi;
  }
  for (int k = 2; k <= 4096; k <<= 1){
    bool upT = ((4*t) & k) == 0;
    for (int j = k >> 1; j >= 256; j >>= 1){
      __syncthreads();
      float4 sv; sv.x=s0; sv.y=s1; sv.z=s2; sv.w=s3;
      int4 av; av.x=a0; av.y=a1; av.z=a2; av.w=a3;
      *(float4*)&ss[4*t] = sv;
      *(int4*)&ii[4*t] = av;
      __syncthreads();
      int pt = t ^ (j >> 2);
      bool eqd = ((t & (j >> 2)) == 0) == upT;
      float4 ps = *(const float4*)&ss[4*pt];
      int4  pa = *(const int4*)&ii[4*pt];
      KV_TAKE(s0,a0,ps.x,pa.x,eqd);
      KV_TAKE(s1,a1,ps.y,pa.y,eqd);
      KV_TAKE(s2,a2,ps.z,pa.z,eqd);
      KV_TAKE(s3,a3,ps.w,pa.w,eqd);
    }
    int jhi = (k >> 1) < 128 ? (k >> 1) : 128;
    for (int j = jhi; j >= 4; j >>= 1){
      int dl = j >> 2;
      bool eqd = ((t & dl) == 0) == upT;
      { float ps=__shfl_xor(s0,dl,64); int pa=__shfl_xor(a0,dl,64); KV_TAKE(s0,a0,ps,pa,eqd); }
      { float ps=__shfl_xor(s1,dl,64); int pa=__shfl_xor(a1,dl,64); KV_TAKE(s1,a1,ps,pa,eqd); }
      { float ps=__shfl_xor(s2,dl,64); int pa=__shfl_xor(a2,dl,64); KV_TAKE(s2,a2,ps,pa,eqd); }
      { float ps=__shfl_xor(s3,dl,64); int pa=__shfl_xor(a3,dl,64); KV_TAKE(s3,a3,ps,pa,eqd); }
    }
    if (k >= 4){
      KV_CMPX(s0,a0,s2,a2,upT);
      KV_CMPX(s1,a1,s3,a3,upT);
      KV_CMPX(s0,a0,s1,a1,upT);
      KV_CMPX(s2,a2,s3,a3,upT);
    } else {
      KV_CMPX(s0,a0,s1,a1,true);
      KV_CMPX(s2,a2,s3,a3,false);
    }
  }
  __syncthreads();
  if (t < 256){
    idx_down[b*MC + 4*t + 0] = a0; inv[b*NT + a0] = 4*t + 0;
    idx_down[b*MC + 4*t + 1] = a1; inv[b*NT + a1] = 4*t + 1;
    idx_down[b*MC + 4*t + 2] = a2; inv[b*NT + a2] = 4*t + 2;
    idx_down[b*MC + 4*t + 3] = a3; inv[b*NT + a3] = 4*t + 3;
  }
}

// cgather (r12): pack the 1024 center rows into dense [MC][256] bf16 buffers
// (+ sqc). Coalesced 512B-per-row copies; bit-preserving. Removes the
// scattered 16B gathers that made r11's assign_mfma ~3x slower than needed.
__global__ __launch_bounds__(256) void cgather(const u16* __restrict__ xh,
                                               const u16* __restrict__ xm,
                                               const u16* __restrict__ xl,
                                               const float* __restrict__ sq,
                                               const int* __restrict__ idx_down,
                                               u16* __restrict__ xch, u16* __restrict__ xcm,
                                               u16* __restrict__ xcl, float* __restrict__ sqc){
  int b = blockIdx.y;
  int m = blockIdx.x*2 + (threadIdx.x >> 7);   // 2 centers/block
  int w = threadIdx.x & 127;                   // u32 word 0..127 (256 u16)
  int src = idx_down[b*MC + m];
  size_t so = ((size_t)b*NT + src)*256;
  size_t dof = ((size_t)b*MC + m)*256;
  ((unsigned*)(xch + dof))[w] = ((const unsigned*)(xh + so))[w];
  ((unsigned*)(xcm + dof))[w] = ((const unsigned*)(xm + so))[w];
  ((unsigned*)(xcl + dof))[w] = ((const unsigned*)(xl + so))[w];
  if (w == 0) sqc[b*MC + m] = sq[b*NT + src];
}

// assign_mfma: center-vs-token distances (1024x4096) from DENSE pre-gathered
// center rows (coalesced staging, same as token side). Identical 6-term MFMA
// arithmetic and lexicographic (d,m) reduction as r11 -> bit-identical to r11
// (which passed with absmax == r10's).
__global__ __launch_bounds__(256) void assign_mfma(const u16* __restrict__ xch,
                                                   const u16* __restrict__ xcm,
                                                   const u16* __restrict__ xcl,
                                                   const u16* __restrict__ xh,
                                                   const u16* __restrict__ xm,
                                                   const u16* __restrict__ xl,
                                                   const float* __restrict__ sq,
                                                   const float* __restrict__ sqc,
                                                   float* __restrict__ Apd, int* __restrict__ Apm){
  __shared__ u16 usmem[24576];
  u16* Au = usmem;
  u16* Bu = usmem + 12288;
  int b = blockIdx.y;
  int ct = blockIdx.x >> 5;
  int jt = blockIdx.x & 31;
  int j0 = jt*128;
  int tid = threadIdx.x;
  int w = tid >> 6, l = tid & 63;
  int lrow = l & 15, lg = l >> 4;
  int li = tid & 127, kq = tid >> 7;
  const size_t base  = (size_t)b*NT*256;
  const size_t basec = (size_t)b*MC*256;
  size_t arow = basec + (size_t)(ct*128 + li)*256 + kq*16;
  size_t brow = base + (size_t)(j0 + li)*256 + kq*16;
  const u16* casrc[3] = {xch, xcm, xcl};
  const u16* cbsrc[3] = {xh, xm, xl};
  int ga0 = ((li*4 + kq*2 + 0) ^ (li & 7)) * 8;
  int ga1 = ((li*4 + kq*2 + 1) ^ (li & 7)) * 8;
  f32x4 acc[2][8];
  f32x4 z; z[0]=0.f; z[1]=0.f; z[2]=0.f; z[3]=0.f;
#pragma unroll
  for (int mr = 0; mr < 2; ++mr)
#pragma unroll
    for (int n0 = 0; n0 < 8; ++n0) acc[mr][n0] = z;
  for (int kc = 0; kc < 8; ++kc){
    int k0 = kc*32;
    __syncthreads();
#pragma unroll
    for (int c = 0; c < 3; ++c){
      bf16x8 a0 = *(const bf16x8*)(casrc[c] + arow + k0);
      bf16x8 a1 = *(const bf16x8*)(casrc[c] + arow + k0 + 8);
      bf16x8 b0 = *(const bf16x8*)(cbsrc[c] + brow + k0);
      bf16x8 b1 = *(const bf16x8*)(cbsrc[c] + brow + k0 + 8);
      *(bf16x8*)(Au + c*4096 + ga0) = a0;
      *(bf16x8*)(Au + c*4096 + ga1) = a1;
      *(bf16x8*)(Bu + c*4096 + ga0) = b0;
      *(bf16x8*)(Bu + c*4096 + ga1) = b1;
    }
    __syncthreads();
    bf16x8 af[2][3];
#pragma unroll
    for (int mr = 0; mr < 2; ++mr){
      int row = w*32 + mr*16 + lrow;
      int off = ((row*4 + lg) ^ (row & 7)) * 8;
#pragma unroll
      for (int c = 0; c < 3; ++c)
        af[mr][c] = *(const bf16x8*)(Au + c*4096 + off);
    }
#pragma unroll
    for (int n0 = 0; n0 < 8; ++n0){
      int rowb = n0*16 + lrow;
      int offb = ((rowb*4 + lg) ^ (rowb & 7)) * 8;
      bf16x8 bh = *(const bf16x8*)(Bu + 0*4096 + offb);
      bf16x8 bm = *(const bf16x8*)(Bu + 1*4096 + offb);
      bf16x8 bl = *(const bf16x8*)(Bu + 2*4096 + offb);
#pragma unroll
      for (int mr = 0; mr < 2; ++mr){
        acc[mr][n0] = __builtin_amdgcn_mfma_f32_16x16x32_bf16(af[mr][0], bh, acc[mr][n0], 0, 0, 0);
        acc[mr][n0] = __builtin_amdgcn_mfma_f32_16x16x32_bf16(af[mr][0], bm, acc[mr][n0], 0, 0, 0);
        acc[mr][n0] = __builtin_amdgcn_mfma_f32_16x16x32_bf16(af[mr][1], bh, acc[mr][n0], 0, 0, 0);
        acc[mr][n0] = __builtin_amdgcn_mfma_f32_16x16x32_bf16(af[mr][1], bm, acc[mr][n0], 0, 0, 0);
        acc[mr][n0] = __builtin_amdgcn_mfma_f32_16x16x32_bf16(af[mr][0], bl, acc[mr][n0], 0, 0, 0);
        acc[mr][n0] = __builtin_amdgcn_mfma_f32_16x16x32_bf16(af[mr][2], bh, acc[mr][n0], 0, 0, 0);
      }
    }
  }
  const float* sqb2 = sq + b*NT;
  const float* sqcb = sqc + b*MC;
  float sqj_c[8];
#pragma unroll
  for (int n0 = 0; n0 < 8; ++n0) sqj_c[n0] = sqb2[j0 + n0*16 + lrow];
  float bd[8]; int bm2[8];
#pragma unroll
  for (int n0 = 0; n0 < 8; ++n0){ bd[n0] = INFINITY; bm2[n0] = 0x7fffffff; }
#pragma unroll
  for (int mr = 0; mr < 2; ++mr)
#pragma unroll
    for (int r = 0; r < 4; ++r){
      int ml = w*32 + mr*16 + lg*4 + r;
      float sqi_v = sqcb[ct*128 + ml];
#pragma unroll
      for (int n0 = 0; n0 < 8; ++n0){
        float v = fmaxf(sqi_v + sqj_c[n0] - 2.0f*acc[mr][n0][r], 0.0f);
        float d = sqrtf(v) * 0.0625f;
        if (d < bd[n0] || (d == bd[n0] && ml < bm2[n0])){ bd[n0] = d; bm2[n0] = ml; }
      }
    }
#pragma unroll
  for (int m = 16; m < 64; m <<= 1)
#pragma unroll
    for (int n0 = 0; n0 < 8; ++n0){
      float od = __shfl_xor(bd[n0], m, 64);
      int   om = __shfl_xor(bm2[n0], m, 64);
      if (od < bd[n0] || (od == bd[n0] && om < bm2[n0])){ bd[n0] = od; bm2[n0] = om; }
    }
  __syncthreads();
  float* sd = (float*)usmem;               // [4][128] floats
  int*   sm = (int*)(usmem + 1024);        // [4][128] ints
  if (lg == 0){
#pragma unroll
    for (int n0 = 0; n0 < 8; ++n0){
      sd[w*128 + n0*16 + lrow] = bd[n0];
      sm[w*128 + n0*16 + lrow] = bm2[n0];
    }
  }
  __syncthreads();
  if (tid < 128){
    float d = sd[tid]; int m = sm[tid];
#pragma unroll
    for (int ww = 1; ww < 4; ++ww){
      float od = sd[ww*128 + tid]; int om = sm[ww*128 + tid];
      if (od < d || (od == d && om < m)){ d = od; m = om; }
    }
    int j = j0 + tid;
    Apd[((size_t)b*NT + j)*8 + ct] = d;
    Apm[((size_t)b*NT + j)*8 + ct] = ct*128 + m;
  }
}

// assign_merge: fold 8 center-tile partials (lexicographic, ascending ct).
__global__ __launch_bounds__(256) void assign_merge(const float* __restrict__ Apd, const int* __restrict__ Apm,
                                                    const int* __restrict__ inv, const float* __restrict__ wt,
                                                    int* __restrict__ idx_cluster, float* __restrict__ allw){
  int b = blockIdx.y;
  int j = blockIdx.x*256 + threadIdx.x;
  const float* pd = Apd + ((size_t)b*NT + j)*8;
  const int*   pm = Apm + ((size_t)b*NT + j)*8;
  float bdv = INFINITY; int bmv = 0x7fffffff;
#pragma unroll
  for (int ct = 0; ct < 8; ++ct){
    float d = pd[ct]; int m = pm[ct];
    if (d < bdv || (d == bdv && m < bmv)){ bdv = d; bmv = m; }
  }
  int iv = inv[b*NT + j];
  int fm = (iv >= 0) ? iv : bmv;
  idx_cluster[b*NT + j] = fm;
  atomicAdd(&allw[b*MC + fm], wt[b*NT + j]);
}

// ---------------- merge + outputs ----------------
__global__ __launch_bounds__(256) void xdown_kernel(const int* __restrict__ idx_cluster,
                                                    const float* __restrict__ wt, const float* __restrict__ allw,
                                                    const float* __restrict__ xt, float* __restrict__ out0){
  int bn = blockIdx.x;
  int d = threadIdx.x;
  int b = bn >> 12;
  int ic = idx_cluster[bn];
  float nw = wt[bn] / (allw[b*MC + ic] + EPS_F);
  float v = xt[(size_t)bn*DOUT + d] * nw;
  atomicAdd(&out0[((size_t)(b*MC + ic))*DOUT + d], v);
}
__global__ __launch_bounds__(256) void out12a_kernel(const int* __restrict__ idx_agg, const int* __restrict__ idx_cluster,
                                                     const float* __restrict__ aggw,
                                                     const float* __restrict__ wt, const float* __restrict__ allw,
                                                     float* __restrict__ awd, int* __restrict__ awdmax,
                                                     float* __restrict__ out1){
  __shared__ float red[4];
  int lin = blockIdx.x * 256 + threadIdx.x;
  int b = lin >> 12;
  int ia = idx_agg[lin];
  int ic = idx_cluster[b*NT + ia];
  out1[lin] = (float)ic;
  float nw = wt[b*NT + ia] / (allw[b*MC + ic] + EPS_F);
  float v = aggw[lin] * nw;
  awd[lin] = v;
  float wv = v;
#pragma unroll
  for (int m = 1; m < 64; m <<= 1) wv = fmaxf(wv, __shfl_xor(wv, m, 64));
  int lane = threadIdx.x & 63, wid = threadIdx.x >> 6;
  if (lane == 0) red[wid] = wv;
  __syncthreads();
  if (threadIdx.x == 0){
    float bm = fmaxf(fmaxf(red[0], red[1]), fmaxf(red[2], red[3]));
    atomicMax(&awdmax[b], __float_as_int(bm));
  }
}
__global__ __launch_bounds__(256) void out2_kernel(const float* __restrict__ awd, const int* __restrict__ awdmax,
                                                   float* __restrict__ out2){
  int lin = blockIdx.x * 256 + threadIdx.x;
  int b = lin >> 12;
  out2[lin] = awd[lin] / __int_as_float(awdmax[b]);
}

extern "C" void kernel_launch(void* const* d_in, const int* in_sizes, int n_in,
                              void* d_out, int out_size, void* d_ws, size_t ws_size,
                              hipStream_t stream) {
  const float* x      = (const float*)d_in[0];
  const float* loc    = (const float*)d_in[1];
  const int*   idxagg = (const int*)d_in[2];
  const float* aggw   = (const float*)d_in[3];
  const float* convw  = (const float*)d_in[7];
  const float* convb  = (const float*)d_in[8];
  const float* skipw  = (const float*)d_in[9];
  const float* lng    = (const float*)d_in[10];
  const float* lnb    = (const float*)d_in[11];
  const float* confw  = (const float*)d_in[12];
  const float* confb  = (const float*)d_in[13];

  char* ws = (char*)d_ws;
  float* w_xmap  = (float*)(ws + OFF_XMAP);
  float* w_cnt   = (float*)(ws + OFF_CNT);
  float* w_tot   = (float*)(ws + OFF_TOT);
  float* w_allw  = (float*)(ws + OFF_ALLW);
  int*   w_vmax  = (int*)  (ws + OFF_VMAX);
  int*   w_awdm  = (int*)  (ws + OFF_AWDM);
  float* w_ymap  = (float*)(ws + OFF_YMAP);
  float* w_xt    = (float*)(ws + OFF_XT);
  float* w_sq    = (float*)(ws + OFF_SQ);
  float* w_den   = (float*)(ws + OFF_DEN);
  float* w_score = (float*)(ws + OFF_SCORE);
  float* w_wt    = (float*)(ws + OFF_WT);
  float* w_awd   = (float*)(ws + OFF_AWD);
  int*   w_idxd  = (int*)  (ws + OFF_IDXD);
  int*   w_idxc  = (int*)  (ws + OFF_IDXC);
  int*   w_inv   = (int*)  (ws + OFF_INV);
  float* w_wtr   = (float*)(ws + OFF_WTR);
  float* w_swt   = (float*)(ws + OFF_SWT);
  float* w_p     = (float*)(ws + OFF_P);
  u16*   w_xh    = (u16*)  (ws + OFF_XH);
  u16*   w_xm    = (u16*)  (ws + OFF_XM);
  u16*   w_xl    = (u16*)  (ws + OFF_XL);
  float* w_dpart = (float*)(ws + OFF_P);    // aliases P (dead after conv_gemm)
  float* w_ppart = (float*)(ws + OFF_PP);
  float* w_apd   = (float*)(ws + OFF_APD);
  int*   w_apm   = (int*)  (ws + OFF_APM);
  u16*   w_xch   = (u16*)  (ws + OFF_XCH);
  u16*   w_xcm   = (u16*)  (ws + OFF_XCM);
  u16*   w_xcl   = (u16*)  (ws + OFF_XCL);
  float* w_sqc   = (float*)(ws + OFF_SQC);

  float* out0 = (float*)d_out;
  float* out1 = out0 + NB*MC*DOUT;
  float* out2 = out1 + NB*NT;

  hipMemsetAsync(ws, 0, ZERO_BYTES, stream);
  hipMemsetAsync(out0, 0, (size_t)NB*MC*DOUT*sizeof(float), stream);

  t2m_scatter<<<NB*NT*CI/256, 256, 0, stream>>>(x, loc, idxagg, aggw, w_xmap, w_cnt, w_tot);
  wprep_kernel<<<1280, 256, 0, stream>>>(convw, skipw, w_wtr, w_swt);
  im2col_kernel<<<2048, 256, 0, stream>>>(w_xmap, w_cnt, w_p);
  conv_gemm<<<dim3(64, 8), 256, 0, stream>>>(w_p, w_wtr, convb, w_ymap);
  skip_kernel<<<NB*NT/8, 256, 0, stream>>>(x, w_swt, w_xt);
  m2t_scatter<<<NB*NT, 256, 0, stream>>>(w_ymap, loc, idxagg, aggw, w_tot, w_xt);
  ln_kernel<<<NB*NT, 256, 0, stream>>>(w_xt, lng, lnb, confw, confb, w_sq, w_wt);
  xsplit_kernel<<<NB*NT*DOUT/512, 256, 0, stream>>>(w_xt, w_xh, w_xm, w_xl);

  dens_mfma   <<<dim3(528, NB), 256, 0, stream>>>(w_xh, w_xm, w_xl, w_sq, w_dpart);
  dens_merge  <<<dim3(16, NB), 256, 0, stream>>>(w_dpart, w_den, w_vmax);
  parent_mfma <<<dim3(528, NB), 256, 0, stream>>>(w_xh, w_xm, w_xl, w_sq, w_den, w_ppart);
  parent_merge<<<dim3(16, NB), 256, 0, stream>>>(w_ppart, w_den, w_vmax, w_score);
  topk_all    <<<NB, 1024, 0, stream>>>(w_score, w_idxd, w_inv);
  cgather     <<<dim3(MC/2, NB), 256, 0, stream>>>(w_xh, w_xm, w_xl, w_sq, w_idxd,
                                                   w_xch, w_xcm, w_xcl, w_sqc);
  assign_mfma <<<dim3(256, NB), 256, 0, stream>>>(w_xch, w_xcm, w_xcl, w_xh, w_xm, w_xl,
                                                  w_sq, w_sqc, w_apd, w_apm);
  assign_merge<<<dim3(16, NB), 256, 0, stream>>>(w_apd, w_apm, w_inv, w_wt, w_idxc, w_allw);

  xdown_kernel<<<NB*NT, 256, 0, stream>>>(w_idxc, w_wt, w_allw, w_xt, out0);
  out12a_kernel<<<NB*NT/256, 256, 0, stream>>>(idxagg, w_idxc, aggw, w_wt, w_allw, w_awd, w_awdm, out1);
  out2_kernel<<<NB*NT/256, 256, 0, stream>>>(w_awd, w_awdm, out2);

  (void)in_sizes; (void)n_in; (void)out_size; (void)ws_size;
}

// Round 15
// 638.803 us; speedup vs baseline: 1.0840x; 1.0770x over previous
//
#include <hip/hip_runtime.h>
#include <math.h>

// B=4, N=4096, C=128, DOUT=256, H=W=64 (conv out 32x32), M=1024, K=5.
#define NB 4
#define NT 4096
#define CI 128
#define DOUT 256
#define HWI 4096
#define HWO 1024
#define MC 1024
#define EPS_F 1e-6f
#define GSZ 16777216ull
#define GSZB 67108864ull

typedef unsigned short u16;
typedef __attribute__((ext_vector_type(8))) short bf16x8;
typedef __attribute__((ext_vector_type(4))) float f32x4;

// ---------------- workspace layout (bytes) ----------------
// zero zone:
static const size_t OFF_XMAP  = 0;                          // 8388608
static const size_t OFF_CNT   = OFF_XMAP + 8388608;         // 65536
static const size_t OFF_TOT   = OFF_CNT  + 65536;           // 65536
static const size_t OFF_ALLW  = OFF_TOT  + 65536;           // 16384
static const size_t OFF_VMAX  = OFF_ALLW + 16384;           // 256
static const size_t OFF_AWDM  = OFF_VMAX + 256;             // 256
static const size_t ZERO_BYTES= OFF_AWDM + 256;
// non-zeroed:
static const size_t OFF_YMAP  = ZERO_BYTES;                 // 4194304
static const size_t OFF_XT    = OFF_YMAP + 4194304;         // 16777216
static const size_t OFF_SQ    = OFF_XT + 16777216;          // 65536
static const size_t OFF_DEN   = OFF_SQ + 65536;
static const size_t OFF_SCORE = OFF_DEN + 65536;
static const size_t OFF_WT    = OFF_SCORE + 65536;
static const size_t OFF_AWD   = OFF_WT + 65536;
static const size_t OFF_IDXD  = OFF_AWD + 65536;            // 16384
static const size_t OFF_IDXC  = OFF_IDXD + 16384;           // 65536
static const size_t OFF_INV   = OFF_IDXC + 65536;           // 65536 (init in topk)
static const size_t OFF_WTR   = OFF_INV + 65536;            // 1179648 (wT[1152][256])
static const size_t OFF_SWT   = OFF_WTR + 1179648;          // 131072 (swT[128][256])
static const size_t OFF_P     = OFF_SWT + 131072;           // 18874368 (P dead after conv -> Dpart aliases)
static const size_t OFF_XH    = OFF_P + 18874368;           // 8388608 (bf16 hi)
static const size_t OFF_XM    = OFF_XH + 8388608;           // 8388608 (bf16 mid)
static const size_t OFF_XL    = OFF_XM + 8388608;           // 8388608 (bf16 lo)
static const size_t OFF_G     = OFF_XL + 8388608;           // ~75.4MB + k*64MiB
// Dpart: [gy][4096 rows][32 tiles][6] floats = 3 MB per slice, aliases OFF_P.
static const size_t DPSTRIDE  = (size_t)NT*32*6;            // floats per slice

// ---------------- helpers ----------------
__device__ __forceinline__ float waveSum(float v){
#pragma unroll
  for (int m = 1; m < 64; m <<= 1) v += __shfl_xor(v, m, 64);
  return v;
}
__device__ __forceinline__ float blockSum256(float v, float* red){
  v = waveSum(v);
  int lane = threadIdx.x & 63, wid = threadIdx.x >> 6;
  __syncthreads();
  if (lane == 0) red[wid] = v;
  __syncthreads();
  return red[0] + red[1] + red[2] + red[3];
}
__device__ __forceinline__ void merge5(float& a0, float& a1, float& a2, float& a3, float& a4,
                                       float b0, float b1, float b2, float b3, float b4){
  float l0=a0,l1=a1,l2=a2,l3=fminf(a3,b4),l4=fminf(a4,b3),l5=b2,l6=b1,l7=b0;
  float t0=fminf(l0,l4), t4=fmaxf(l0,l4);
  float t1=fminf(l1,l5), t5=fmaxf(l1,l5);
  float t2=fminf(l2,l6), t6=fmaxf(l2,l6);
  float t3=fminf(l3,l7), t7=fmaxf(l3,l7);
  float u0=fminf(t0,t2), u2=fmaxf(t0,t2);
  float u1=fminf(t1,t3), u3=fmaxf(t1,t3);
  float u4=fminf(t4,t6);
  float u5=fminf(t5,t7);
  a0=fminf(u0,u1); a1=fmaxf(u0,u1);
  a2=fminf(u2,u3); a3=fmaxf(u2,u3);
  a4=fminf(u4,u5);
}
__device__ __forceinline__ void ins5(float v, float& t0, float& t1, float& t2, float& t3, float& t4){
  t4 = fminf(t4, v);
  float a;
  a = fminf(t3,t4); t4 = fmaxf(t3,t4); t3 = a;
  a = fminf(t2,t3); t3 = fmaxf(t2,t3); t2 = a;
  a = fminf(t1,t2); t2 = fmaxf(t1,t2); t1 = a;
  a = fminf(t0,t1); t1 = fmaxf(t0,t1); t0 = a;
}
__device__ __forceinline__ int grid_cell(float lx, float ly, int dim){
  lx = (fminf(fmaxf(lx, -1.f), 1.f) + 1.f) * 0.5f;
  ly = (fminf(fmaxf(ly, -1.f), 1.f) + 1.f) * 0.5f;
  float s = (float)(dim - 1);
  int col = (int)rintf(lx * s); col = min(max(col, 0), dim - 1);
  int row = (int)rintf(ly * s); row = min(max(row, 0), dim - 1);
  return row * dim + col;
}

// ---------------- front-end kernels ----------------
__global__ __launch_bounds__(256) void t2m_scatter(const float* __restrict__ x,
                                                   const float* __restrict__ loc,
                                                   const int* __restrict__ idx_agg,
                                                   const float* __restrict__ aggw,
                                                   float* __restrict__ xmap, float* __restrict__ cnt,
                                                   float* __restrict__ tot){
  int lin = blockIdx.x * 256 + threadIdx.x;
  int c  = lin & 127;
  int bn = lin >> 7;
  int b  = bn >> 12;
  float lx = loc[(size_t)bn*2 + 0];
  float ly = loc[(size_t)bn*2 + 1];
  int cell = grid_cell(lx, ly, 64);
  int ia = idx_agg[bn];
  float val = x[((size_t)(b*NT + ia))*CI + c];
  atomicAdd(&xmap[((size_t)(b*HWI + cell))*CI + c], val);
  if (c == 0) atomicAdd(&cnt[b*HWI + cell], 1.0f);
  if (c == 1) atomicAdd(&tot[b*NT + ia], aggw[bn]);
}

// fused weight prep: wT[k][d] = conv_w[d][k]; swT[c][d] = skip_w[d][c]
__global__ __launch_bounds__(256) void wprep_kernel(const float* __restrict__ cw, const float* __restrict__ sw,
                                                    float* __restrict__ wT, float* __restrict__ swT){
  int lin = blockIdx.x * 256 + threadIdx.x;
  if (lin < 1152*256){
    int k = lin >> 8, d = lin & 255;
    wT[lin] = cw[(size_t)d*1152 + k];
  } else {
    int i = lin - 1152*256;
    int c = i >> 8, d = i & 255;
    swT[i] = sw[d*128 + c];
  }
}

__global__ __launch_bounds__(256) void im2col_kernel(const float* __restrict__ xmap,
                                                     const float* __restrict__ cnt,
                                                     float* __restrict__ P){
  int tid = threadIdx.x;
  int c = tid & 127, n2 = tid >> 7;
  int n = blockIdx.x * 2 + n2;
  int b = n >> 10, rem = n & 1023;
  int oh = rem >> 5, ow = rem & 31;
  const float* xb = xmap + (size_t)b*HWI*CI;
  const float* cb_ = cnt + (size_t)b*HWI;
  float* prow = P + (size_t)n*1152 + c*9;
#pragma unroll
  for (int kh = 0; kh < 3; ++kh){
    int ih = oh*2 - 1 + kh;
#pragma unroll
    for (int kw = 0; kw < 3; ++kw){
      int iw = ow*2 - 1 + kw;
      bool inb = (ih >= 0) && (ih < 64) && (iw >= 0) && (iw < 64);
      float v = 0.f;
      if (inb){
        int cell = ih*64 + iw;
        v = xb[(size_t)cell*CI + c] / (cb_[cell] + EPS_F);
      }
      prow[kh*3 + kw] = v;
    }
  }
}

// conv GEMM: 64(n) x 32(d) tiles. Grid (64 n0, 8 d0) for A-panel L2 locality.
__global__ __launch_bounds__(256) void conv_gemm(const float* __restrict__ P,
                                                 const float* __restrict__ wT,
                                                 const float* __restrict__ cb,
                                                 float* __restrict__ ymap){
  __shared__ float As[16][64];
  __shared__ float Bs[16][32];
  int n0 = blockIdx.x * 64, d0 = blockIdx.y * 32;
  int tid = threadIdx.x;
  int tx = tid & 15, ty = tid >> 4;
  int ln = tid & 63, kq = tid >> 6;
  int bkr = tid >> 3, bc4 = (tid & 7) * 4;
  float4 pav = *(const float4*)(P + (size_t)(n0+ln)*1152 + kq*4);
  float4 pbv;
  if (tid < 128) pbv = *(const float4*)(wT + (size_t)bkr*256 + d0 + bc4);
  float acc[4][2] = {{0}};
  for (int kt = 0; kt < 72; ++kt){
    __syncthreads();
    As[kq*4+0][ln]=pav.x; As[kq*4+1][ln]=pav.y; As[kq*4+2][ln]=pav.z; As[kq*4+3][ln]=pav.w;
    if (tid < 128) *(float4*)&Bs[bkr][bc4] = pbv;
    __syncthreads();
    if (kt < 71){
      int k2 = (kt + 1) * 16;
      pav = *(const float4*)(P + (size_t)(n0+ln)*1152 + k2 + kq*4);
      if (tid < 128) pbv = *(const float4*)(wT + (size_t)(k2 + bkr)*256 + d0 + bc4);
    }
#pragma unroll
    for (int k = 0; k < 16; ++k){
      float ar[4];
      *(float4*)ar = *(const float4*)&As[k][ty*4];
      float b0 = Bs[k][tx*2], b1 = Bs[k][tx*2+1];
#pragma unroll
      for (int r = 0; r < 4; ++r){ acc[r][0] += ar[r]*b0; acc[r][1] += ar[r]*b1; }
    }
  }
  float c0 = cb[d0 + tx*2], c1 = cb[d0 + tx*2 + 1];
#pragma unroll
  for (int r = 0; r < 4; ++r){
    float2 o; o.x = acc[r][0] + c0; o.y = acc[r][1] + c1;
    *(float2*)(ymap + (size_t)(n0 + ty*4 + r)*DOUT + d0 + tx*2) = o;
  }
}

// xt = x @ skip_w.T via transposed weights (coalesced); c ascending -> bit-identical
__global__ __launch_bounds__(256) void skip_kernel(const float* __restrict__ x,
                                                   const float* __restrict__ swT,
                                                   float* __restrict__ xt){
  int rowbase = blockIdx.x * 8;
  int d = threadIdx.x;
  __shared__ float xr[8*128];
  ((float4*)xr)[d] = ((const float4*)(x + (size_t)rowbase*CI))[d];
  __syncthreads();
  float acc[8] = {0,0,0,0,0,0,0,0};
  for (int c = 0; c < 128; ++c){
    float w = swT[c*256 + d];
#pragma unroll
    for (int r = 0; r < 8; ++r) acc[r] += w * xr[r*128 + c];
  }
  for (int r = 0; r < 8; ++r) xt[(size_t)(rowbase + r)*DOUT + d] = acc[r];
}

__global__ __launch_bounds__(256) void m2t_scatter(const float* __restrict__ ymap,
                                                   const float* __restrict__ loc,
                                                   const int* __restrict__ idx_agg,
                                                   const float* __restrict__ aggw,
                                                   const float* __restrict__ tot,
                                                   float* __restrict__ xt){
  int bn = blockIdx.x;
  int d = threadIdx.x;
  int b = bn >> 12;
  float lx = loc[(size_t)bn*2 + 0];
  float ly = loc[(size_t)bn*2 + 1];
  int cell = grid_cell(lx, ly, 32);
  int ia = idx_agg[bn];
  float w = aggw[bn] / (tot[b*NT + ia] + EPS_F);
  float val = ymap[((size_t)(b*HWO + cell))*DOUT + d] * w;
  atomicAdd(&xt[((size_t)(b*NT + ia))*DOUT + d], val);
}

__global__ __launch_bounds__(256) void ln_kernel(float* __restrict__ xt,
                                                 const float* __restrict__ g,
                                                 const float* __restrict__ bta,
                                                 const float* __restrict__ cw,
                                                 const float* __restrict__ cb,
                                                 float* __restrict__ sq, float* __restrict__ wt){
  __shared__ float red[4];
  int row = blockIdx.x;
  int d = threadIdx.x;
  float v = xt[(size_t)row*DOUT + d];
  float mu = blockSum256(v, red) * (1.0f/256.0f);
  float xc = v - mu;
  float var = blockSum256(xc*xc, red) * (1.0f/256.0f);
  float rn = 1.0f / sqrtf(var + 1e-5f);
  float y = xc * rn * g[d] + bta[d];
  xt[(size_t)row*DOUT + d] = y;
  float s2 = blockSum256(y*y, red);
  float cf = blockSum256(y*cw[d], red);
  if (d == 0){ sq[row] = s2; wt[row] = expf(cf + cb[0]); }
}

// xsplit: exact 3-way bf16 truncation split xt = hi + mid + lo (24 mantissa bits).
__global__ __launch_bounds__(256) void xsplit_kernel(const float* __restrict__ xt,
                                                     u16* __restrict__ xh,
                                                     u16* __restrict__ xm,
                                                     u16* __restrict__ xl){
  int idx = blockIdx.x*256 + threadIdx.x;
  float2 v = *(const float2*)(xt + (size_t)idx*2);
  unsigned ph, pm, pl;
  {
    unsigned u = __float_as_uint(v.x);
    unsigned h0 = u >> 16;
    float r1 = v.x - __uint_as_float(u & 0xFFFF0000u);
    unsigned u1 = __float_as_uint(r1);
    unsigned m0 = u1 >> 16;
    float r2 = r1 - __uint_as_float(u1 & 0xFFFF0000u);
    unsigned l0 = __float_as_uint(r2) >> 16;
    unsigned u2 = __float_as_uint(v.y);
    unsigned h1 = u2 >> 16;
    float s1 = v.y - __uint_as_float(u2 & 0xFFFF0000u);
    unsigned u3 = __float_as_uint(s1);
    unsigned m1 = u3 >> 16;
    float s2 = s1 - __uint_as_float(u3 & 0xFFFF0000u);
    unsigned l1 = __float_as_uint(s2) >> 16;
    ph = h0 | (h1 << 16); pm = m0 | (m1 << 16); pl = l0 | (l1 << 16);
  }
  *(unsigned*)(xh + (size_t)idx*2) = ph;
  *(unsigned*)(xm + (size_t)idx*2) = pm;
  *(unsigned*)(xl + (size_t)idx*2) = pl;
}

// ---------------- clustering ----------------
// gram via MFMA bf16x3 (6 cross terms, fp32 MFMA accum) + FUSED density
// partials: per tile, each row's 5 smallest distances + max reduced from the
// accumulators into Dpart[row][tilecol][6]. (r10 architecture: G materialized
// once; the r11/r12 G-free variants and r13 coop fusion all measured slower
// or failed -- this is the empirically best verified configuration.)
__global__ __launch_bounds__(256) void gram_mfma(const u16* __restrict__ xh,
                                                 const u16* __restrict__ xm,
                                                 const u16* __restrict__ xl,
                                                 const float* __restrict__ sq,
                                                 float* __restrict__ G,
                                                 float* __restrict__ Dpart,
                                                 int b_base, size_t gstride){
  __shared__ u16 usmem[24576];         // A comps @ 0,4096,8192; B comps @ 12288+...
  u16* Au = usmem;
  u16* Bu = usmem + 12288;
  int b = b_base + blockIdx.y;
  float* Gb = G + (size_t)blockIdx.y*gstride;
  float* Dp = Dpart + (size_t)blockIdx.y*DPSTRIDE;
  int t = blockIdx.x;
  int ti = 0, accu = 0;
  while (accu + ti + 1 <= t){ accu += ti + 1; ++ti; }
  int tj = t - accu;
  int i0 = ti*128, j0 = tj*128;
  int tid = threadIdx.x;
  int w = tid >> 6, l = tid & 63;
  int lrow = l & 15, lg = l >> 4;
  int li = tid & 127, kq = tid >> 7;      // staging: row, k-half
  const size_t base = (size_t)b*NT*256;
  size_t arow = base + (size_t)(i0 + li)*256 + kq*16;
  size_t brow = base + (size_t)(j0 + li)*256 + kq*16;
  const u16* csrc[3] = {xh, xm, xl};
  int ga0 = ((li*4 + kq*2 + 0) ^ (li & 7)) * 8;
  int ga1 = ((li*4 + kq*2 + 1) ^ (li & 7)) * 8;
  f32x4 acc[2][8];
  f32x4 z; z[0]=0.f; z[1]=0.f; z[2]=0.f; z[3]=0.f;
#pragma unroll
  for (int mr = 0; mr < 2; ++mr)
#pragma unroll
    for (int n0 = 0; n0 < 8; ++n0) acc[mr][n0] = z;
  for (int kc = 0; kc < 8; ++kc){
    int k0 = kc*32;
    __syncthreads();
#pragma unroll
    for (int c = 0; c < 3; ++c){
      const u16* s = csrc[c];
      bf16x8 a0 = *(const bf16x8*)(s + arow + k0);
      bf16x8 a1 = *(const bf16x8*)(s + arow + k0 + 8);
      bf16x8 b0 = *(const bf16x8*)(s + brow + k0);
      bf16x8 b1 = *(const bf16x8*)(s + brow + k0 + 8);
      *(bf16x8*)(Au + c*4096 + ga0) = a0;
      *(bf16x8*)(Au + c*4096 + ga1) = a1;
      *(bf16x8*)(Bu + c*4096 + ga0) = b0;
      *(bf16x8*)(Bu + c*4096 + ga1) = b1;
    }
    __syncthreads();
    bf16x8 af[2][3];
#pragma unroll
    for (int mr = 0; mr < 2; ++mr){
      int row = w*32 + mr*16 + lrow;
      int off = ((row*4 + lg) ^ (row & 7)) * 8;
#pragma unroll
      for (int c = 0; c < 3; ++c)
        af[mr][c] = *(const bf16x8*)(Au + c*4096 + off);
    }
#pragma unroll
    for (int n0 = 0; n0 < 8; ++n0){
      int rowb = n0*16 + lrow;
      int offb = ((rowb*4 + lg) ^ (rowb & 7)) * 8;
      bf16x8 bh = *(const bf16x8*)(Bu + 0*4096 + offb);
      bf16x8 bm = *(const bf16x8*)(Bu + 1*4096 + offb);
      bf16x8 bl = *(const bf16x8*)(Bu + 2*4096 + offb);
#pragma unroll
      for (int mr = 0; mr < 2; ++mr){
        acc[mr][n0] = __builtin_amdgcn_mfma_f32_16x16x32_bf16(af[mr][0], bh, acc[mr][n0], 0, 0, 0);
        acc[mr][n0] = __builtin_amdgcn_mfma_f32_16x16x32_bf16(af[mr][0], bm, acc[mr][n0], 0, 0, 0);
        acc[mr][n0] = __builtin_amdgcn_mfma_f32_16x16x32_bf16(af[mr][1], bh, acc[mr][n0], 0, 0, 0);
        acc[mr][n0] = __builtin_amdgcn_mfma_f32_16x16x32_bf16(af[mr][1], bm, acc[mr][n0], 0, 0, 0);
        acc[mr][n0] = __builtin_amdgcn_mfma_f32_16x16x32_bf16(af[mr][0], bl, acc[mr][n0], 0, 0, 0);
        acc[mr][n0] = __builtin_amdgcn_mfma_f32_16x16x32_bf16(af[mr][2], bh, acc[mr][n0], 0, 0, 0);
      }
    }
  }
  const float* sqb2 = sq + b*NT;
  // ---- i-side density partials: rows of this block x cols j0..j0+127 ----
  {
    float sqj_c[8];
#pragma unroll
    for (int n0 = 0; n0 < 8; ++n0) sqj_c[n0] = sqb2[j0 + n0*16 + lrow];
#pragma unroll
    for (int mr = 0; mr < 2; ++mr)
#pragma unroll
      for (int r = 0; r < 4; ++r){
        int row = i0 + w*32 + mr*16 + lg*4 + r;
        float sqi_v = sqb2[row];
        float t0=INFINITY,t1=INFINITY,t2=INFINITY,t3=INFINITY,t4=INFINITY;
        float mx = 0.f;
#pragma unroll
        for (int n0 = 0; n0 < 8; ++n0){
          float v = fmaxf(sqi_v + sqj_c[n0] - 2.0f*acc[mr][n0][r], 0.0f);
          mx = fmaxf(mx, v);
          ins5(v,t0,t1,t2,t3,t4);
        }
#pragma unroll
        for (int m = 1; m < 16; m <<= 1){
          float b0=__shfl_xor(t0,m,64), b1=__shfl_xor(t1,m,64), b2=__shfl_xor(t2,m,64),
                b3=__shfl_xor(t3,m,64), b4=__shfl_xor(t4,m,64);
          merge5(t0,t1,t2,t3,t4,b0,b1,b2,b3,b4);
          mx = fmaxf(mx, __shfl_xor(mx,m,64));
        }
        if (lrow == 0){
          float* dpp = Dp + ((size_t)row*32 + tj)*6;
          dpp[0]=t0; dpp[1]=t1; dpp[2]=t2; dpp[3]=t3; dpp[4]=t4; dpp[5]=mx;
        }
      }
  }
  // direct (i,j) tile store
#pragma unroll
  for (int mr = 0; mr < 2; ++mr)
#pragma unroll
    for (int n0 = 0; n0 < 8; ++n0)
#pragma unroll
      for (int r = 0; r < 4; ++r)
        Gb[(size_t)(i0 + w*32 + mr*16 + lg*4 + r)*NT + j0 + n0*16 + lrow] = acc[mr][n0][r];
  if (ti != tj){
    // transposed (j,i) tile via chunked LDS transpose: 4 chunks of 32 cols.
    float* T = (float*)usmem;            // [32][129] = 16.5 KB, aliases staging
    int q = tid >> 3, u = tid & 7;
    float sqi_u[16];
#pragma unroll
    for (int e = 0; e < 16; ++e) sqi_u[e] = sqb2[i0 + u*16 + e];
#pragma unroll
    for (int cc = 0; cc < 4; ++cc){
      __syncthreads();
#pragma unroll
      for (int nn = 0; nn < 2; ++nn){
        int n0 = cc*2 + nn;
#pragma unroll
        for (int mr = 0; mr < 2; ++mr)
#pragma unroll
          for (int r = 0; r < 4; ++r)
            T[(nn*16 + lrow)*129 + w*32 + mr*16 + lg*4 + r] = acc[mr][n0][r];
      }
      __syncthreads();
      const float* Trow = &T[q*129 + u*16];
      float* dst = Gb + (size_t)(j0 + cc*32 + q)*NT + i0 + u*16;
      float gv[16];
#pragma unroll
      for (int e = 0; e < 16; ++e) gv[e] = Trow[e];
      float4 o0, o1, o2, o3;
      o0.x=gv[0]; o0.y=gv[1]; o0.z=gv[2]; o0.w=gv[3];
      o1.x=gv[4]; o1.y=gv[5]; o1.z=gv[6]; o1.w=gv[7];
      o2.x=gv[8]; o2.y=gv[9]; o2.z=gv[10]; o2.w=gv[11];
      o3.x=gv[12]; o3.y=gv[13]; o3.z=gv[14]; o3.w=gv[15];
      *(float4*)dst = o0; *(float4*)(dst + 4) = o1;
      *(float4*)(dst + 8) = o2; *(float4*)(dst + 12) = o3;
      // ---- j-side density partial: mirror row j over cols i0+u*16..+15 ----
      {
        int jr = j0 + cc*32 + q;
        float sqj_m = sqb2[jr];
        float t0=INFINITY,t1=INFINITY,t2=INFINITY,t3=INFINITY,t4=INFINITY;
        float mx = 0.f;
#pragma unroll
        for (int e = 0; e < 16; ++e){
          float v = fmaxf(sqj_m + sqi_u[e] - 2.0f*gv[e], 0.0f);
          mx = fmaxf(mx, v);
          ins5(v,t0,t1,t2,t3,t4);
        }
#pragma unroll
        for (int m = 1; m < 8; m <<= 1){
          float b0=__shfl_xor(t0,m,64), b1=__shfl_xor(t1,m,64), b2=__shfl_xor(t2,m,64),
                b3=__shfl_xor(t3,m,64), b4=__shfl_xor(t4,m,64);
          merge5(t0,t1,t2,t3,t4,b0,b1,b2,b3,b4);
          mx = fmaxf(mx, __shfl_xor(mx,m,64));
        }
        if (u == 0){
          float* dpp = Dp + ((size_t)jr*32 + ti)*6;
          dpp[0]=t0; dpp[1]=t1; dpp[2]=t2; dpp[3]=t3; dpp[4]=t4; dpp[5]=mx;
        }
      }
    }
  }
}

// dens_merge: fold the 32 sorted per-tile partials per row -> density + vmax.
__global__ __launch_bounds__(256) void dens_merge(const float* __restrict__ Dpart,
                                                  float* __restrict__ density, int* __restrict__ vmax,
                                                  int b_base){
  int b = b_base + blockIdx.y;
  const float* Dp = Dpart + (size_t)blockIdx.y*DPSTRIDE;
  int row = blockIdx.x*256 + threadIdx.x;
  const float* p = Dp + (size_t)row*32*6;
  float t0=INFINITY,t1=INFINITY,t2=INFINITY,t3=INFINITY,t4=INFINITY;
  float mx = 0.f;
#pragma unroll 4
  for (int tt = 0; tt < 32; ++tt){
    merge5(t0,t1,t2,t3,t4, p[tt*6+0], p[tt*6+1], p[tt*6+2], p[tt*6+3], p[tt*6+4]);
    mx = fmaxf(mx, p[tt*6+5]);
  }
  float d0=sqrtf(t0)*0.0625f, d1=sqrtf(t1)*0.0625f, d2=sqrtf(t2)*0.0625f,
        d3=sqrtf(t3)*0.0625f, d4=sqrtf(t4)*0.0625f;
  float s = d0*d0; s += d1*d1; s += d2*d2; s += d3*d3; s += d4*d4;
  density[b*NT + row] = expf(-(s / 5.0f));
#pragma unroll
  for (int m = 1; m < 64; m <<= 1) mx = fmaxf(mx, __shfl_xor(mx, m, 64));
  if ((threadIdx.x & 63) == 0) atomicMax(vmax + b, __float_as_int(mx));
}

// parent: one row per wave, deep-prefetch (G reads; L3-stream-bound).
__global__ __launch_bounds__(256) void parent_all(const float* __restrict__ G, size_t gstride,
                                                  const float* __restrict__ sq,
                                                  const float* __restrict__ density, const int* __restrict__ vmax,
                                                  float* __restrict__ score, int b_base){
  int b = b_base + blockIdx.y;
  const float* Gb = G + (size_t)blockIdx.y*gstride;
  int i = blockIdx.x*4 + (threadIdx.x >> 6);
  int lane = threadIdx.x & 63;
  const float* sqb = sq + b*NT;
  const float* den = density + b*NT;
  float sqi = sqb[i];
  float di = den[i];
  const float4* row4 = (const float4*)(Gb + (size_t)i*NT);
  const float4* sq4  = (const float4*)sqb;
  const float4* dn4  = (const float4*)den;
  float4 ga[8], gb2[8];
#pragma unroll
  for (int p = 0; p < 8; ++p) ga[p] = row4[p*64 + lane];
#pragma unroll
  for (int p = 0; p < 8; ++p) gb2[p] = row4[(8+p)*64 + lane];
  float minv = INFINITY;
#pragma unroll
  for (int p = 0; p < 8; ++p){
    float4 g4 = ga[p];
    float4 s4 = sq4[p*64 + lane];
    float4 d4 = dn4[p*64 + lane];
    float v0 = fmaxf(sqi + s4.x - 2.0f*g4.x, 0.0f);
    float v1 = fmaxf(sqi + s4.y - 2.0f*g4.y, 0.0f);
    float v2 = fmaxf(sqi + s4.z - 2.0f*g4.z, 0.0f);
    float v3 = fmaxf(sqi + s4.w - 2.0f*g4.w, 0.0f);
    minv = fminf(minv, (d4.x > di) ? v0 : INFINITY);
    minv = fminf(minv, (d4.y > di) ? v1 : INFINITY);
    minv = fminf(minv, (d4.z > di) ? v2 : INFINITY);
    minv = fminf(minv, (d4.w > di) ? v3 : INFINITY);
  }
#pragma unroll
  for (int p = 0; p < 8; ++p){
    float4 g4 = gb2[p];
    float4 s4 = sq4[(8+p)*64 + lane];
    float4 d4 = dn4[(8+p)*64 + lane];
    float v0 = fmaxf(sqi + s4.x - 2.0f*g4.x, 0.0f);
    float v1 = fmaxf(sqi + s4.y - 2.0f*g4.y, 0.0f);
    float v2 = fmaxf(sqi + s4.z - 2.0f*g4.z, 0.0f);
    float v3 = fmaxf(sqi + s4.w - 2.0f*g4.w, 0.0f);
    minv = fminf(minv, (d4.x > di) ? v0 : INFINITY);
    minv = fminf(minv, (d4.y > di) ? v1 : INFINITY);
    minv = fminf(minv, (d4.z > di) ? v2 : INFINITY);
    minv = fminf(minv, (d4.w > di) ? v3 : INFINITY);
  }
#pragma unroll
  for (int m = 1; m < 64; m <<= 1) minv = fminf(minv, __shfl_xor(minv,m,64));
  if (lane == 0){
    float dmax = sqrtf(__int_as_float(vmax[b])) * 0.0625f;
    float dp = isinf(minv) ? dmax : sqrtf(minv) * 0.0625f;
    score[b*NT + i] = dp * di;
  }
}

// ---------------- topk: hybrid bitonic sort 4096 (score desc, idx asc) ----------------
__device__ __forceinline__ bool kv_lt(float s1, int a1, float s2, int a2){
  return (s1 > s2) || (s1 == s2 && a1 < a2);
}
#define KV_CMPX(sx,ax,sy,ay,up) do{ bool _l = kv_lt(sx,ax,sy,ay); \
  if (_l != (up)) { float _ts=sx; sx=sy; sy=_ts; int _ta=ax; ax=ay; ay=_ta; } }while(0)
#define KV_TAKE(sx,ax,ps,pa,eqd) do{ bool _keep = kv_lt(sx,ax,ps,pa) == (eqd); \
  if(!_keep){ sx=(ps); ax=(pa); } }while(0)

__global__ __launch_bounds__(1024) void topk_all(const float* __restrict__ score, int* __restrict__ idx_down,
                                                 int* __restrict__ inv, int b_base){
  __shared__ float ss[4096];
  __shared__ int ii[4096];
  int b = b_base + blockIdx.x;
  int t = threadIdx.x;
  float s0,s1,s2,s3; int a0,a1,a2,a3;
  {
    float4 v = *(const float4*)(score + b*NT + 4*t);
    s0=v.x; s1=v.y; s2=v.z; s3=v.w;
    a0=4*t; a1=4*t+1; a2=4*t+2; a3=4*t+3;
    int4 mi; mi.x=-1; mi.y=-1; mi.z=-1; mi.w=-1;
    *(int4*)(inv + b*NT + 4*t) = mi;
  }
  for (int k = 2; k <= 4096; k <<= 1){
    bool upT = ((4*t) & k) == 0;
    for (int j = k >> 1; j >= 256; j >>= 1){
      __syncthreads();
      float4 sv; sv.x=s0; sv.y=s1; sv.z=s2; sv.w=s3;
      int4 av; av.x=a0; av.y=a1; av.z=a2; av.w=a3;
      *(float4*)&ss[4*t] = sv;
      *(int4*)&ii[4*t] = av;
      __syncthreads();
      int pt = t ^ (j >> 2);
      bool eqd = ((t & (j >> 2)) == 0) == upT;
      float4 ps = *(const float4*)&ss[4*pt];
      int4  pa = *(const int4*)&ii[4*pt];
      KV_TAKE(s0,a0,ps.x,pa.x,eqd);
      KV_TAKE(s1,a1,ps.y,pa.y,eqd);
      KV_TAKE(s2,a2,ps.z,pa.z,eqd);
      KV_TAKE(s3,a3,ps.w,pa.w,eqd);
    }
    int jhi = (k >> 1) < 128 ? (k >> 1) : 128;
    for (int j = jhi; j >= 4; j >>= 1){
      int dl = j >> 2;
      bool eqd = ((t & dl) == 0) == upT;
      { float ps=__shfl_xor(s0,dl,64); int pa=__shfl_xor(a0,dl,64); KV_TAKE(s0,a0,ps,pa,eqd); }
      { float ps=__shfl_xor(s1,dl,64); int pa=__shfl_xor(a1,dl,64); KV_TAKE(s1,a1,ps,pa,eqd); }
      { float ps=__shfl_xor(s2,dl,64); int pa=__shfl_xor(a2,dl,64); KV_TAKE(s2,a2,ps,pa,eqd); }
      { float ps=__shfl_xor(s3,dl,64); int pa=__shfl_xor(a3,dl,64); KV_TAKE(s3,a3,ps,pa,eqd); }
    }
    if (k >= 4){
      KV_CMPX(s0,a0,s2,a2,upT);
      KV_CMPX(s1,a1,s3,a3,upT);
      KV_CMPX(s0,a0,s1,a1,upT);
      KV_CMPX(s2,a2,s3,a3,upT);
    } else {
      KV_CMPX(s0,a0,s1,a1,true);
      KV_CMPX(s2,a2,s3,a3,false);
    }
  }
  __syncthreads();
  if (t < 256){
    idx_down[b*MC + 4*t + 0] = a0; inv[b*NT + a0] = 4*t + 0;
    idx_down[b*MC + 4*t + 1] = a1; inv[b*NT + a1] = 4*t + 1;
    idx_down[b*MC + 4*t + 2] = a2; inv[b*NT + a2] = 4*t + 2;
    idx_down[b*MC + 4*t + 3] = a3; inv[b*NT + a3] = 4*t + 3;
  }
}

// assign: block = 16 j x 16 m-chunks (64 m each, ascending); grid 256 x gy.
__global__ __launch_bounds__(256) void assign_all(const float* __restrict__ G, size_t gstride,
                                                  const float* __restrict__ sq,
                                                  const int* __restrict__ idx_down, const int* __restrict__ inv,
                                                  const float* __restrict__ wt,
                                                  int* __restrict__ idx_cluster, float* __restrict__ allw,
                                                  int b_base){
  int b = b_base + blockIdx.y;
  const float* Gb = G + (size_t)blockIdx.y*gstride;
  int jl = threadIdx.x & 15, mq = threadIdx.x >> 4;
  int j = blockIdx.x * 16 + jl;
  const float* sqb = sq + b*NT;
  float sqj = sqb[j];
  const int* idb = idx_down + b*MC;
  float bestd = INFINITY; int bestm = 0x7fffffff;
  for (int m = mq*64; m < mq*64 + 64; ++m){
    int im = idb[m];
    float g = Gb[(size_t)im*NT + j];
    float v = fmaxf(sqb[im] + sqj - 2.0f*g, 0.0f);
    float d = sqrtf(v) * 0.0625f;
    if (d < bestd){ bestd = d; bestm = m; }
  }
  __shared__ float ld[16][17];
  __shared__ int lm[16][17];
  ld[mq][jl] = bestd; lm[mq][jl] = bestm;
  __syncthreads();
  if (mq == 0){
    for (int q = 1; q < 16; ++q){
      float d2 = ld[q][jl]; int m2 = lm[q][jl];
      if (d2 < bestd || (d2 == bestd && m2 < bestm)){ bestd = d2; bestm = m2; }
    }
    int iv = inv[b*NT + j];
    int final_m = (iv >= 0) ? iv : bestm;
    idx_cluster[b*NT + j] = final_m;
    atomicAdd(&allw[b*MC + final_m], wt[b*NT + j]);
  }
}

// ---------------- merge + outputs ----------------
__global__ __launch_bounds__(256) void xdown_kernel(const int* __restrict__ idx_cluster,
                                                    const float* __restrict__ wt, const float* __restrict__ allw,
                                                    const float* __restrict__ xt, float* __restrict__ out0){
  int bn = blockIdx.x;
  int d = threadIdx.x;
  int b = bn >> 12;
  int ic = idx_cluster[bn];
  float nw = wt[bn] / (allw[b*MC + ic] + EPS_F);
  float v = xt[(size_t)bn*DOUT + d] * nw;
  atomicAdd(&out0[((size_t)(b*MC + ic))*DOUT + d], v);
}
__global__ __launch_bounds__(256) void out12a_kernel(const int* __restrict__ idx_agg, const int* __restrict__ idx_cluster,
                                                     const float* __restrict__ aggw,
                                                     const float* __restrict__ wt, const float* __restrict__ allw,
                                                     float* __restrict__ awd, int* __restrict__ awdmax,
                                                     float* __restrict__ out1){
  __shared__ float red[4];
  int lin = blockIdx.x * 256 + threadIdx.x;
  int b = lin >> 12;
  int ia = idx_agg[lin];
  int ic = idx_cluster[b*NT + ia];
  out1[lin] = (float)ic;
  float nw = wt[b*NT + ia] / (allw[b*MC + ic] + EPS_F);
  float v = aggw[lin] * nw;
  awd[lin] = v;
  float wv = v;
#pragma unroll
  for (int m = 1; m < 64; m <<= 1) wv = fmaxf(wv, __shfl_xor(wv, m, 64));
  int lane = threadIdx.x & 63, wid = threadIdx.x >> 6;
  if (lane == 0) red[wid] = wv;
  __syncthreads();
  if (threadIdx.x == 0){
    float bm = fmaxf(fmaxf(red[0], red[1]), fmaxf(red[2], red[3]));
    atomicMax(&awdmax[b], __float_as_int(bm));
  }
}
__global__ __launch_bounds__(256) void out2_kernel(const float* __restrict__ awd, const int* __restrict__ awdmax,
                                                   float* __restrict__ out2){
  int lin = blockIdx.x * 256 + threadIdx.x;
  int b = lin >> 12;
  out2[lin] = awd[lin] / __int_as_float(awdmax[b]);
}

extern "C" void kernel_launch(void* const* d_in, const int* in_sizes, int n_in,
                              void* d_out, int out_size, void* d_ws, size_t ws_size,
                              hipStream_t stream) {
  const float* x      = (const float*)d_in[0];
  const float* loc    = (const float*)d_in[1];
  const int*   idxagg = (const int*)d_in[2];
  const float* aggw   = (const float*)d_in[3];
  const float* convw  = (const float*)d_in[7];
  const float* convb  = (const float*)d_in[8];
  const float* skipw  = (const float*)d_in[9];
  const float* lng    = (const float*)d_in[10];
  const float* lnb    = (const float*)d_in[11];
  const float* confw  = (const float*)d_in[12];
  const float* confb  = (const float*)d_in[13];

  char* ws = (char*)d_ws;
  float* w_xmap  = (float*)(ws + OFF_XMAP);
  float* w_cnt   = (float*)(ws + OFF_CNT);
  float* w_tot   = (float*)(ws + OFF_TOT);
  float* w_allw  = (float*)(ws + OFF_ALLW);
  int*   w_vmax  = (int*)  (ws + OFF_VMAX);
  int*   w_awdm  = (int*)  (ws + OFF_AWDM);
  float* w_ymap  = (float*)(ws + OFF_YMAP);
  float* w_xt    = (float*)(ws + OFF_XT);
  float* w_sq    = (float*)(ws + OFF_SQ);
  float* w_den   = (float*)(ws + OFF_DEN);
  float* w_score = (float*)(ws + OFF_SCORE);
  float* w_wt    = (float*)(ws + OFF_WT);
  float* w_awd   = (float*)(ws + OFF_AWD);
  int*   w_idxd  = (int*)  (ws + OFF_IDXD);
  int*   w_idxc  = (int*)  (ws + OFF_IDXC);
  int*   w_inv   = (int*)  (ws + OFF_INV);
  float* w_wtr   = (float*)(ws + OFF_WTR);
  float* w_swt   = (float*)(ws + OFF_SWT);
  float* w_p     = (float*)(ws + OFF_P);
  u16*   w_xh    = (u16*)  (ws + OFF_XH);
  u16*   w_xm    = (u16*)  (ws + OFF_XM);
  u16*   w_xl    = (u16*)  (ws + OFF_XL);
  float* w_g     = (float*)(ws + OFF_G);
  float* w_dpart = (float*)(ws + OFF_P);   // aliases P (dead after conv_gemm)

  int gcount = 1;
  for (int k = 4; k >= 1; --k){
    if (OFF_G + (size_t)k*GSZB <= ws_size){ gcount = k; break; }
  }

  float* out0 = (float*)d_out;
  float* out1 = out0 + NB*MC*DOUT;
  float* out2 = out1 + NB*NT;

  hipMemsetAsync(ws, 0, ZERO_BYTES, stream);
  hipMemsetAsync(out0, 0, (size_t)NB*MC*DOUT*sizeof(float), stream);

  t2m_scatter<<<NB*NT*CI/256, 256, 0, stream>>>(x, loc, idxagg, aggw, w_xmap, w_cnt, w_tot);
  wprep_kernel<<<1280, 256, 0, stream>>>(convw, skipw, w_wtr, w_swt);
  im2col_kernel<<<2048, 256, 0, stream>>>(w_xmap, w_cnt, w_p);
  conv_gemm<<<dim3(64, 8), 256, 0, stream>>>(w_p, w_wtr, convb, w_ymap);
  skip_kernel<<<NB*NT/8, 256, 0, stream>>>(x, w_swt, w_xt);
  m2t_scatter<<<NB*NT, 256, 0, stream>>>(w_ymap, loc, idxagg, aggw, w_tot, w_xt);
  ln_kernel<<<NB*NT, 256, 0, stream>>>(w_xt, lng, lnb, confw, confb, w_sq, w_wt);
  xsplit_kernel<<<NB*NT*DOUT/512, 256, 0, stream>>>(w_xt, w_xh, w_xm, w_xl);

  for (int g0 = 0; g0 < NB; g0 += gcount){
    int gy = (NB - g0 < gcount) ? (NB - g0) : gcount;
    gram_mfma  <<<dim3(528, gy), 256, 0, stream>>>(w_xh, w_xm, w_xl, w_sq, w_g, w_dpart, g0, GSZ);
    dens_merge <<<dim3(16, gy), 256, 0, stream>>>(w_dpart, w_den, w_vmax, g0);
    parent_all <<<dim3(1024, gy), 256, 0, stream>>>(w_g, GSZ, w_sq, w_den, w_vmax, w_score, g0);
    topk_all   <<<gy, 1024, 0, stream>>>(w_score, w_idxd, w_inv, g0);
    assign_all <<<dim3(256, gy), 256, 0, stream>>>(w_g, GSZ, w_sq, w_idxd, w_inv, w_wt, w_idxc, w_allw, g0);
  }

  xdown_kernel<<<NB*NT, 256, 0, stream>>>(w_idxc, w_wt, w_allw, w_xt, out0);
  out12a_kernel<<<NB*NT/256, 256, 0, stream>>>(idxagg, w_idxc, aggw, w_wt, w_allw, w_awd, w_awdm, out1);
  out2_kernel<<<NB*NT/256, 256, 0, stream>>>(w_awd, w_awdm, out2);

  (void)in_sizes; (void)n_in; (void)out_size;
}

// Round 16
// 607.079 us; speedup vs baseline: 1.1406x; 1.0523x over previous
//
#include <hip/hip_runtime.h>
#include <math.h>

// B=4, N=4096, C=128, DOUT=256, H=W=64 (conv out 32x32), M=1024, K=5.
#define NB 4
#define NT 4096
#define CI 128
#define DOUT 256
#define HWI 4096
#define HWO 1024
#define MC 1024
#define EPS_F 1e-6f
#define GSZ 16777216ull
#define GSZB 67108864ull

typedef unsigned short u16;
typedef __attribute__((ext_vector_type(8))) short bf16x8;
typedef __attribute__((ext_vector_type(4))) float f32x4;

// ---------------- workspace layout (bytes) ----------------
// zero zone:
static const size_t OFF_XMAP  = 0;                          // 8388608
static const size_t OFF_CNT   = OFF_XMAP + 8388608;         // 65536
static const size_t OFF_TOT   = OFF_CNT  + 65536;           // 65536
static const size_t OFF_ALLW  = OFF_TOT  + 65536;           // 16384
static const size_t OFF_VMAX  = OFF_ALLW + 16384;           // 256
static const size_t OFF_AWDM  = OFF_VMAX + 256;             // 256
static const size_t ZERO_BYTES= OFF_AWDM + 256;
// non-zeroed:
static const size_t OFF_YMAP  = ZERO_BYTES;                 // 4194304
static const size_t OFF_XT    = OFF_YMAP + 4194304;         // 16777216
static const size_t OFF_SQ    = OFF_XT + 16777216;          // 65536
static const size_t OFF_DEN   = OFF_SQ + 65536;
static const size_t OFF_SCORE = OFF_DEN + 65536;
static const size_t OFF_WT    = OFF_SCORE + 65536;
static const size_t OFF_AWD   = OFF_WT + 65536;
static const size_t OFF_IDXD  = OFF_AWD + 65536;            // 16384
static const size_t OFF_IDXC  = OFF_IDXD + 16384;           // 65536
static const size_t OFF_INV   = OFF_IDXC + 65536;           // 65536 (init in topk)
static const size_t OFF_WTR   = OFF_INV + 65536;            // 1179648 (wT[1152][256])
static const size_t OFF_SWT   = OFF_WTR + 1179648;          // 131072 (swT[128][256])
static const size_t OFF_P     = OFF_SWT + 131072;           // 18874368 (P dead after conv -> Dpart aliases)
static const size_t OFF_XH    = OFF_P + 18874368;           // 8388608 (bf16 hi)
static const size_t OFF_XM    = OFF_XH + 8388608;           // 8388608 (bf16 mid)
static const size_t OFF_XL    = OFF_XM + 8388608;           // 8388608 (bf16 lo)
static const size_t OFF_G     = OFF_XL + 8388608;           // ~75.4MB + k*64MiB
// Dpart: [gy][4096 rows][32 tiles][6] floats = 3 MB per slice, aliases OFF_P.
static const size_t DPSTRIDE  = (size_t)NT*32*6;            // floats per slice

// ---------------- helpers ----------------
__device__ __forceinline__ float waveSum(float v){
#pragma unroll
  for (int m = 1; m < 64; m <<= 1) v += __shfl_xor(v, m, 64);
  return v;
}
__device__ __forceinline__ float blockSum256(float v, float* red){
  v = waveSum(v);
  int lane = threadIdx.x & 63, wid = threadIdx.x >> 6;
  __syncthreads();
  if (lane == 0) red[wid] = v;
  __syncthreads();
  return red[0] + red[1] + red[2] + red[3];
}
__device__ __forceinline__ void merge5(float& a0, float& a1, float& a2, float& a3, float& a4,
                                       float b0, float b1, float b2, float b3, float b4){
  float l0=a0,l1=a1,l2=a2,l3=fminf(a3,b4),l4=fminf(a4,b3),l5=b2,l6=b1,l7=b0;
  float t0=fminf(l0,l4), t4=fmaxf(l0,l4);
  float t1=fminf(l1,l5), t5=fmaxf(l1,l5);
  float t2=fminf(l2,l6), t6=fmaxf(l2,l6);
  float t3=fminf(l3,l7), t7=fmaxf(l3,l7);
  float u0=fminf(t0,t2), u2=fmaxf(t0,t2);
  float u1=fminf(t1,t3), u3=fmaxf(t1,t3);
  float u4=fminf(t4,t6);
  float u5=fminf(t5,t7);
  a0=fminf(u0,u1); a1=fmaxf(u0,u1);
  a2=fminf(u2,u3); a3=fmaxf(u2,u3);
  a4=fminf(u4,u5);
}
__device__ __forceinline__ void ins5(float v, float& t0, float& t1, float& t2, float& t3, float& t4){
  t4 = fminf(t4, v);
  float a;
  a = fminf(t3,t4); t4 = fmaxf(t3,t4); t3 = a;
  a = fminf(t2,t3); t3 = fmaxf(t2,t3); t2 = a;
  a = fminf(t1,t2); t2 = fmaxf(t1,t2); t1 = a;
  a = fminf(t0,t1); t1 = fmaxf(t0,t1); t0 = a;
}
__device__ __forceinline__ int grid_cell(float lx, float ly, int dim){
  lx = (fminf(fmaxf(lx, -1.f), 1.f) + 1.f) * 0.5f;
  ly = (fminf(fmaxf(ly, -1.f), 1.f) + 1.f) * 0.5f;
  float s = (float)(dim - 1);
  int col = (int)rintf(lx * s); col = min(max(col, 0), dim - 1);
  int row = (int)rintf(ly * s); row = min(max(row, 0), dim - 1);
  return row * dim + col;
}

// ---------------- front-end kernels ----------------
__global__ __launch_bounds__(256) void t2m_scatter(const float* __restrict__ x,
                                                   const float* __restrict__ loc,
                                                   const int* __restrict__ idx_agg,
                                                   const float* __restrict__ aggw,
                                                   float* __restrict__ xmap, float* __restrict__ cnt,
                                                   float* __restrict__ tot){
  int lin = blockIdx.x * 256 + threadIdx.x;
  int c  = lin & 127;
  int bn = lin >> 7;
  int b  = bn >> 12;
  float lx = loc[(size_t)bn*2 + 0];
  float ly = loc[(size_t)bn*2 + 1];
  int cell = grid_cell(lx, ly, 64);
  int ia = idx_agg[bn];
  float val = x[((size_t)(b*NT + ia))*CI + c];
  atomicAdd(&xmap[((size_t)(b*HWI + cell))*CI + c], val);
  if (c == 0) atomicAdd(&cnt[b*HWI + cell], 1.0f);
  if (c == 1) atomicAdd(&tot[b*NT + ia], aggw[bn]);
}

// fused weight prep: wT[k][d] = conv_w[d][k]; swT[c][d] = skip_w[d][c]
__global__ __launch_bounds__(256) void wprep_kernel(const float* __restrict__ cw, const float* __restrict__ sw,
                                                    float* __restrict__ wT, float* __restrict__ swT){
  int lin = blockIdx.x * 256 + threadIdx.x;
  if (lin < 1152*256){
    int k = lin >> 8, d = lin & 255;
    wT[lin] = cw[(size_t)d*1152 + k];
  } else {
    int i = lin - 1152*256;
    int c = i >> 8, d = i & 255;
    swT[i] = sw[d*128 + c];
  }
}

__global__ __launch_bounds__(256) void im2col_kernel(const float* __restrict__ xmap,
                                                     const float* __restrict__ cnt,
                                                     float* __restrict__ P){
  int tid = threadIdx.x;
  int c = tid & 127, n2 = tid >> 7;
  int n = blockIdx.x * 2 + n2;
  int b = n >> 10, rem = n & 1023;
  int oh = rem >> 5, ow = rem & 31;
  const float* xb = xmap + (size_t)b*HWI*CI;
  const float* cb_ = cnt + (size_t)b*HWI;
  float* prow = P + (size_t)n*1152 + c*9;
#pragma unroll
  for (int kh = 0; kh < 3; ++kh){
    int ih = oh*2 - 1 + kh;
#pragma unroll
    for (int kw = 0; kw < 3; ++kw){
      int iw = ow*2 - 1 + kw;
      bool inb = (ih >= 0) && (ih < 64) && (iw >= 0) && (iw < 64);
      float v = 0.f;
      if (inb){
        int cell = ih*64 + iw;
        v = xb[(size_t)cell*CI + c] / (cb_[cell] + EPS_F);
      }
      prow[kh*3 + kw] = v;
    }
  }
}

// conv GEMM: 64(n) x 32(d) tiles. Grid (64 n0, 8 d0) for A-panel L2 locality.
__global__ __launch_bounds__(256) void conv_gemm(const float* __restrict__ P,
                                                 const float* __restrict__ wT,
                                                 const float* __restrict__ cb,
                                                 float* __restrict__ ymap){
  __shared__ float As[16][64];
  __shared__ float Bs[16][32];
  int n0 = blockIdx.x * 64, d0 = blockIdx.y * 32;
  int tid = threadIdx.x;
  int tx = tid & 15, ty = tid >> 4;
  int ln = tid & 63, kq = tid >> 6;
  int bkr = tid >> 3, bc4 = (tid & 7) * 4;
  float4 pav = *(const float4*)(P + (size_t)(n0+ln)*1152 + kq*4);
  float4 pbv;
  if (tid < 128) pbv = *(const float4*)(wT + (size_t)bkr*256 + d0 + bc4);
  float acc[4][2] = {{0}};
  for (int kt = 0; kt < 72; ++kt){
    __syncthreads();
    As[kq*4+0][ln]=pav.x; As[kq*4+1][ln]=pav.y; As[kq*4+2][ln]=pav.z; As[kq*4+3][ln]=pav.w;
    if (tid < 128) *(float4*)&Bs[bkr][bc4] = pbv;
    __syncthreads();
    if (kt < 71){
      int k2 = (kt + 1) * 16;
      pav = *(const float4*)(P + (size_t)(n0+ln)*1152 + k2 + kq*4);
      if (tid < 128) pbv = *(const float4*)(wT + (size_t)(k2 + bkr)*256 + d0 + bc4);
    }
#pragma unroll
    for (int k = 0; k < 16; ++k){
      float ar[4];
      *(float4*)ar = *(const float4*)&As[k][ty*4];
      float b0 = Bs[k][tx*2], b1 = Bs[k][tx*2+1];
#pragma unroll
      for (int r = 0; r < 4; ++r){ acc[r][0] += ar[r]*b0; acc[r][1] += ar[r]*b1; }
    }
  }
  float c0 = cb[d0 + tx*2], c1 = cb[d0 + tx*2 + 1];
#pragma unroll
  for (int r = 0; r < 4; ++r){
    float2 o; o.x = acc[r][0] + c0; o.y = acc[r][1] + c1;
    *(float2*)(ymap + (size_t)(n0 + ty*4 + r)*DOUT + d0 + tx*2) = o;
  }
}

// xt = x @ skip_w.T via transposed weights (coalesced); c ascending -> bit-identical
__global__ __launch_bounds__(256) void skip_kernel(const float* __restrict__ x,
                                                   const float* __restrict__ swT,
                                                   float* __restrict__ xt){
  int rowbase = blockIdx.x * 8;
  int d = threadIdx.x;
  __shared__ float xr[8*128];
  ((float4*)xr)[d] = ((const float4*)(x + (size_t)rowbase*CI))[d];
  __syncthreads();
  float acc[8] = {0,0,0,0,0,0,0,0};
  for (int c = 0; c < 128; ++c){
    float w = swT[c*256 + d];
#pragma unroll
    for (int r = 0; r < 8; ++r) acc[r] += w * xr[r*128 + c];
  }
  for (int r = 0; r < 8; ++r) xt[(size_t)(rowbase + r)*DOUT + d] = acc[r];
}

__global__ __launch_bounds__(256) void m2t_scatter(const float* __restrict__ ymap,
                                                   const float* __restrict__ loc,
                                                   const int* __restrict__ idx_agg,
                                                   const float* __restrict__ aggw,
                                                   const float* __restrict__ tot,
                                                   float* __restrict__ xt){
  int bn = blockIdx.x;
  int d = threadIdx.x;
  int b = bn >> 12;
  float lx = loc[(size_t)bn*2 + 0];
  float ly = loc[(size_t)bn*2 + 1];
  int cell = grid_cell(lx, ly, 32);
  int ia = idx_agg[bn];
  float w = aggw[bn] / (tot[b*NT + ia] + EPS_F);
  float val = ymap[((size_t)(b*HWO + cell))*DOUT + d] * w;
  atomicAdd(&xt[((size_t)(b*NT + ia))*DOUT + d], val);
}

__global__ __launch_bounds__(256) void ln_kernel(float* __restrict__ xt,
                                                 const float* __restrict__ g,
                                                 const float* __restrict__ bta,
                                                 const float* __restrict__ cw,
                                                 const float* __restrict__ cb,
                                                 float* __restrict__ sq, float* __restrict__ wt){
  __shared__ float red[4];
  int row = blockIdx.x;
  int d = threadIdx.x;
  float v = xt[(size_t)row*DOUT + d];
  float mu = blockSum256(v, red) * (1.0f/256.0f);
  float xc = v - mu;
  float var = blockSum256(xc*xc, red) * (1.0f/256.0f);
  float rn = 1.0f / sqrtf(var + 1e-5f);
  float y = xc * rn * g[d] + bta[d];
  xt[(size_t)row*DOUT + d] = y;
  float s2 = blockSum256(y*y, red);
  float cf = blockSum256(y*cw[d], red);
  if (d == 0){ sq[row] = s2; wt[row] = expf(cf + cb[0]); }
}

// xsplit: exact 3-way bf16 truncation split xt = hi + mid + lo (24 mantissa bits).
__global__ __launch_bounds__(256) void xsplit_kernel(const float* __restrict__ xt,
                                                     u16* __restrict__ xh,
                                                     u16* __restrict__ xm,
                                                     u16* __restrict__ xl){
  int idx = blockIdx.x*256 + threadIdx.x;
  float2 v = *(const float2*)(xt + (size_t)idx*2);
  unsigned ph, pm, pl;
  {
    unsigned u = __float_as_uint(v.x);
    unsigned h0 = u >> 16;
    float r1 = v.x - __uint_as_float(u & 0xFFFF0000u);
    unsigned u1 = __float_as_uint(r1);
    unsigned m0 = u1 >> 16;
    float r2 = r1 - __uint_as_float(u1 & 0xFFFF0000u);
    unsigned l0 = __float_as_uint(r2) >> 16;
    unsigned u2 = __float_as_uint(v.y);
    unsigned h1 = u2 >> 16;
    float s1 = v.y - __uint_as_float(u2 & 0xFFFF0000u);
    unsigned u3 = __float_as_uint(s1);
    unsigned m1 = u3 >> 16;
    float s2 = s1 - __uint_as_float(u3 & 0xFFFF0000u);
    unsigned l1 = __float_as_uint(s2) >> 16;
    ph = h0 | (h1 << 16); pm = m0 | (m1 << 16); pl = l0 | (l1 << 16);
  }
  *(unsigned*)(xh + (size_t)idx*2) = ph;
  *(unsigned*)(xm + (size_t)idx*2) = pm;
  *(unsigned*)(xl + (size_t)idx*2) = pl;
}

// ---------------- clustering ----------------
// gram via MFMA bf16x3 + fused density partials (r10 architecture).
// r16: staging switched from reg round-trip (12 global float4 loads + 12
// ds_write_b128 per thread per k-chunk) to DIRECT global->LDS DMA via
// __builtin_amdgcn_global_load_lds(16B). The LDS dest is wave-uniform base +
// lane*16 (linear), so the per-lane GLOBAL source carries the inverse of the
// old XOR-swizzle write map: slot s holds global granule g = s ^ (r&7) with
// r = 2*(s>>3) or +1 selected by (g>>2)==r (XOR key only touches bits 0-2).
// Same bytes -> same LDS slots -> fragment reads and all arithmetic
// BIT-IDENTICAL to r15. __syncthreads drains vmcnt before compute (m97
// pattern, which beat reg-prefetch variants on MI355X).
__global__ __launch_bounds__(256) void gram_mfma(const u16* __restrict__ xh,
                                                 const u16* __restrict__ xm,
                                                 const u16* __restrict__ xl,
                                                 const float* __restrict__ sq,
                                                 float* __restrict__ G,
                                                 float* __restrict__ Dpart,
                                                 int b_base, size_t gstride){
  __shared__ u16 usmem[24576];         // A comps @ 0,4096,8192; B comps @ 12288+...
  u16* Au = usmem;
  u16* Bu = usmem + 12288;
  int b = b_base + blockIdx.y;
  float* Gb = G + (size_t)blockIdx.y*gstride;
  float* Dp = Dpart + (size_t)blockIdx.y*DPSTRIDE;
  int t = blockIdx.x;
  int ti = 0, accu = 0;
  while (accu + ti + 1 <= t){ accu += ti + 1; ++ti; }
  int tj = t - accu;
  int i0 = ti*128, j0 = tj*128;
  int tid = threadIdx.x;
  int w = tid >> 6, l = tid & 63;
  int lrow = l & 15, lg = l >> 4;
  const size_t base = (size_t)b*NT*256;
  const u16* csrc[3] = {xh, xm, xl};
  // precompute the 12 DMA descriptors for this wave: (side,comp,window),
  // window in {w, 4+w}; per-lane global pointer = inverse-swizzled granule.
  const u16* gptr[12];
  u16* lptr[12];
  {
    int ci = 0;
#pragma unroll
    for (int side = 0; side < 2; ++side)
#pragma unroll
      for (int c = 0; c < 3; ++c)
#pragma unroll
        for (int wv = 0; wv < 2; ++wv){
          int win = w + wv*4;
          int s = win*64 + l;               // LDS slot (granule index 0..511)
          int r = (s >> 3) * 2;             // candidate row (even)
          int g = s ^ (r & 7);
          if ((g >> 2) != r){ r += 1; g = s ^ (r & 7); }
          int q = g & 3;                    // granule within row
          int rowbase = side ? j0 : i0;
          gptr[ci] = csrc[c] + base + (size_t)(rowbase + r)*256 + q*8;
          lptr[ci] = (side ? Bu : Au) + c*4096 + win*512;
          ++ci;
        }
  }
  f32x4 acc[2][8];
  f32x4 z; z[0]=0.f; z[1]=0.f; z[2]=0.f; z[3]=0.f;
#pragma unroll
  for (int mr = 0; mr < 2; ++mr)
#pragma unroll
    for (int n0 = 0; n0 < 8; ++n0) acc[mr][n0] = z;
  for (int kc = 0; kc < 8; ++kc){
    __syncthreads();                        // previous chunk's LDS reads done
#pragma unroll
    for (int ci = 0; ci < 12; ++ci)
      __builtin_amdgcn_global_load_lds((const void*)(gptr[ci] + kc*32),
                                       (void*)lptr[ci], 16, 0, 0);
    __syncthreads();                        // drains vmcnt(0): LDS data ready
    bf16x8 af[2][3];
#pragma unroll
    for (int mr = 0; mr < 2; ++mr){
      int row = w*32 + mr*16 + lrow;
      int off = ((row*4 + lg) ^ (row & 7)) * 8;
#pragma unroll
      for (int c = 0; c < 3; ++c)
        af[mr][c] = *(const bf16x8*)(Au + c*4096 + off);
    }
#pragma unroll
    for (int n0 = 0; n0 < 8; ++n0){
      int rowb = n0*16 + lrow;
      int offb = ((rowb*4 + lg) ^ (rowb & 7)) * 8;
      bf16x8 bh = *(const bf16x8*)(Bu + 0*4096 + offb);
      bf16x8 bm = *(const bf16x8*)(Bu + 1*4096 + offb);
      bf16x8 bl = *(const bf16x8*)(Bu + 2*4096 + offb);
#pragma unroll
      for (int mr = 0; mr < 2; ++mr){
        acc[mr][n0] = __builtin_amdgcn_mfma_f32_16x16x32_bf16(af[mr][0], bh, acc[mr][n0], 0, 0, 0);
        acc[mr][n0] = __builtin_amdgcn_mfma_f32_16x16x32_bf16(af[mr][0], bm, acc[mr][n0], 0, 0, 0);
        acc[mr][n0] = __builtin_amdgcn_mfma_f32_16x16x32_bf16(af[mr][1], bh, acc[mr][n0], 0, 0, 0);
        acc[mr][n0] = __builtin_amdgcn_mfma_f32_16x16x32_bf16(af[mr][1], bm, acc[mr][n0], 0, 0, 0);
        acc[mr][n0] = __builtin_amdgcn_mfma_f32_16x16x32_bf16(af[mr][0], bl, acc[mr][n0], 0, 0, 0);
        acc[mr][n0] = __builtin_amdgcn_mfma_f32_16x16x32_bf16(af[mr][2], bh, acc[mr][n0], 0, 0, 0);
      }
    }
  }
  const float* sqb2 = sq + b*NT;
  // ---- i-side density partials: rows of this block x cols j0..j0+127 ----
  {
    float sqj_c[8];
#pragma unroll
    for (int n0 = 0; n0 < 8; ++n0) sqj_c[n0] = sqb2[j0 + n0*16 + lrow];
#pragma unroll
    for (int mr = 0; mr < 2; ++mr)
#pragma unroll
      for (int r = 0; r < 4; ++r){
        int row = i0 + w*32 + mr*16 + lg*4 + r;
        float sqi_v = sqb2[row];
        float t0=INFINITY,t1=INFINITY,t2=INFINITY,t3=INFINITY,t4=INFINITY;
        float mx = 0.f;
#pragma unroll
        for (int n0 = 0; n0 < 8; ++n0){
          float v = fmaxf(sqi_v + sqj_c[n0] - 2.0f*acc[mr][n0][r], 0.0f);
          mx = fmaxf(mx, v);
          ins5(v,t0,t1,t2,t3,t4);
        }
#pragma unroll
        for (int m = 1; m < 16; m <<= 1){
          float b0=__shfl_xor(t0,m,64), b1=__shfl_xor(t1,m,64), b2=__shfl_xor(t2,m,64),
                b3=__shfl_xor(t3,m,64), b4=__shfl_xor(t4,m,64);
          merge5(t0,t1,t2,t3,t4,b0,b1,b2,b3,b4);
          mx = fmaxf(mx, __shfl_xor(mx,m,64));
        }
        if (lrow == 0){
          float* dpp = Dp + ((size_t)row*32 + tj)*6;
          dpp[0]=t0; dpp[1]=t1; dpp[2]=t2; dpp[3]=t3; dpp[4]=t4; dpp[5]=mx;
        }
      }
  }
  // direct (i,j) tile store
#pragma unroll
  for (int mr = 0; mr < 2; ++mr)
#pragma unroll
    for (int n0 = 0; n0 < 8; ++n0)
#pragma unroll
      for (int r = 0; r < 4; ++r)
        Gb[(size_t)(i0 + w*32 + mr*16 + lg*4 + r)*NT + j0 + n0*16 + lrow] = acc[mr][n0][r];
  if (ti != tj){
    // transposed (j,i) tile via chunked LDS transpose: 4 chunks of 32 cols.
    float* T = (float*)usmem;            // [32][129] = 16.5 KB, aliases staging
    int q = tid >> 3, u = tid & 7;
    float sqi_u[16];
#pragma unroll
    for (int e = 0; e < 16; ++e) sqi_u[e] = sqb2[i0 + u*16 + e];
#pragma unroll
    for (int cc = 0; cc < 4; ++cc){
      __syncthreads();
#pragma unroll
      for (int nn = 0; nn < 2; ++nn){
        int n0 = cc*2 + nn;
#pragma unroll
        for (int mr = 0; mr < 2; ++mr)
#pragma unroll
          for (int r = 0; r < 4; ++r)
            T[(nn*16 + lrow)*129 + w*32 + mr*16 + lg*4 + r] = acc[mr][n0][r];
      }
      __syncthreads();
      const float* Trow = &T[q*129 + u*16];
      float* dst = Gb + (size_t)(j0 + cc*32 + q)*NT + i0 + u*16;
      float gv[16];
#pragma unroll
      for (int e = 0; e < 16; ++e) gv[e] = Trow[e];
      float4 o0, o1, o2, o3;
      o0.x=gv[0]; o0.y=gv[1]; o0.z=gv[2]; o0.w=gv[3];
      o1.x=gv[4]; o1.y=gv[5]; o1.z=gv[6]; o1.w=gv[7];
      o2.x=gv[8]; o2.y=gv[9]; o2.z=gv[10]; o2.w=gv[11];
      o3.x=gv[12]; o3.y=gv[13]; o3.z=gv[14]; o3.w=gv[15];
      *(float4*)dst = o0; *(float4*)(dst + 4) = o1;
      *(float4*)(dst + 8) = o2; *(float4*)(dst + 12) = o3;
      // ---- j-side density partial: mirror row j over cols i0+u*16..+15 ----
      {
        int jr = j0 + cc*32 + q;
        float sqj_m = sqb2[jr];
        float t0=INFINITY,t1=INFINITY,t2=INFINITY,t3=INFINITY,t4=INFINITY;
        float mx = 0.f;
#pragma unroll
        for (int e = 0; e < 16; ++e){
          float v = fmaxf(sqj_m + sqi_u[e] - 2.0f*gv[e], 0.0f);
          mx = fmaxf(mx, v);
          ins5(v,t0,t1,t2,t3,t4);
        }
#pragma unroll
        for (int m = 1; m < 8; m <<= 1){
          float b0=__shfl_xor(t0,m,64), b1=__shfl_xor(t1,m,64), b2=__shfl_xor(t2,m,64),
                b3=__shfl_xor(t3,m,64), b4=__shfl_xor(t4,m,64);
          merge5(t0,t1,t2,t3,t4,b0,b1,b2,b3,b4);
          mx = fmaxf(mx, __shfl_xor(mx,m,64));
        }
        if (u == 0){
          float* dpp = Dp + ((size_t)jr*32 + ti)*6;
          dpp[0]=t0; dpp[1]=t1; dpp[2]=t2; dpp[3]=t3; dpp[4]=t4; dpp[5]=mx;
        }
      }
    }
  }
}

// dens_merge: fold the 32 sorted per-tile partials per row -> density + vmax.
__global__ __launch_bounds__(256) void dens_merge(const float* __restrict__ Dpart,
                                                  float* __restrict__ density, int* __restrict__ vmax,
                                                  int b_base){
  int b = b_base + blockIdx.y;
  const float* Dp = Dpart + (size_t)blockIdx.y*DPSTRIDE;
  int row = blockIdx.x*256 + threadIdx.x;
  const float* p = Dp + (size_t)row*32*6;
  float t0=INFINITY,t1=INFINITY,t2=INFINITY,t3=INFINITY,t4=INFINITY;
  float mx = 0.f;
#pragma unroll 4
  for (int tt = 0; tt < 32; ++tt){
    merge5(t0,t1,t2,t3,t4, p[tt*6+0], p[tt*6+1], p[tt*6+2], p[tt*6+3], p[tt*6+4]);
    mx = fmaxf(mx, p[tt*6+5]);
  }
  float d0=sqrtf(t0)*0.0625f, d1=sqrtf(t1)*0.0625f, d2=sqrtf(t2)*0.0625f,
        d3=sqrtf(t3)*0.0625f, d4=sqrtf(t4)*0.0625f;
  float s = d0*d0; s += d1*d1; s += d2*d2; s += d3*d3; s += d4*d4;
  density[b*NT + row] = expf(-(s / 5.0f));
#pragma unroll
  for (int m = 1; m < 64; m <<= 1) mx = fmaxf(mx, __shfl_xor(mx, m, 64));
  if ((threadIdx.x & 63) == 0) atomicMax(vmax + b, __float_as_int(mx));
}

// parent: one row per wave, deep-prefetch (G reads; L3-stream-bound).
__global__ __launch_bounds__(256) void parent_all(const float* __restrict__ G, size_t gstride,
                                                  const float* __restrict__ sq,
                                                  const float* __restrict__ density, const int* __restrict__ vmax,
                                                  float* __restrict__ score, int b_base){
  int b = b_base + blockIdx.y;
  const float* Gb = G + (size_t)blockIdx.y*gstride;
  int i = blockIdx.x*4 + (threadIdx.x >> 6);
  int lane = threadIdx.x & 63;
  const float* sqb = sq + b*NT;
  const float* den = density + b*NT;
  float sqi = sqb[i];
  float di = den[i];
  const float4* row4 = (const float4*)(Gb + (size_t)i*NT);
  const float4* sq4  = (const float4*)sqb;
  const float4* dn4  = (const float4*)den;
  float4 ga[8], gb2[8];
#pragma unroll
  for (int p = 0; p < 8; ++p) ga[p] = row4[p*64 + lane];
#pragma unroll
  for (int p = 0; p < 8; ++p) gb2[p] = row4[(8+p)*64 + lane];
  float minv = INFINITY;
#pragma unroll
  for (int p = 0; p < 8; ++p){
    float4 g4 = ga[p];
    float4 s4 = sq4[p*64 + lane];
    float4 d4 = dn4[p*64 + lane];
    float v0 = fmaxf(sqi + s4.x - 2.0f*g4.x, 0.0f);
    float v1 = fmaxf(sqi + s4.y - 2.0f*g4.y, 0.0f);
    float v2 = fmaxf(sqi + s4.z - 2.0f*g4.z, 0.0f);
    float v3 = fmaxf(sqi + s4.w - 2.0f*g4.w, 0.0f);
    minv = fminf(minv, (d4.x > di) ? v0 : INFINITY);
    minv = fminf(minv, (d4.y > di) ? v1 : INFINITY);
    minv = fminf(minv, (d4.z > di) ? v2 : INFINITY);
    minv = fminf(minv, (d4.w > di) ? v3 : INFINITY);
  }
#pragma unroll
  for (int p = 0; p < 8; ++p){
    float4 g4 = gb2[p];
    float4 s4 = sq4[(8+p)*64 + lane];
    float4 d4 = dn4[(8+p)*64 + lane];
    float v0 = fmaxf(sqi + s4.x - 2.0f*g4.x, 0.0f);
    float v1 = fmaxf(sqi + s4.y - 2.0f*g4.y, 0.0f);
    float v2 = fmaxf(sqi + s4.z - 2.0f*g4.z, 0.0f);
    float v3 = fmaxf(sqi + s4.w - 2.0f*g4.w, 0.0f);
    minv = fminf(minv, (d4.x > di) ? v0 : INFINITY);
    minv = fminf(minv, (d4.y > di) ? v1 : INFINITY);
    minv = fminf(minv, (d4.z > di) ? v2 : INFINITY);
    minv = fminf(minv, (d4.w > di) ? v3 : INFINITY);
  }
#pragma unroll
  for (int m = 1; m < 64; m <<= 1) minv = fminf(minv, __shfl_xor(minv,m,64));
  if (lane == 0){
    float dmax = sqrtf(__int_as_float(vmax[b])) * 0.0625f;
    float dp = isinf(minv) ? dmax : sqrtf(minv) * 0.0625f;
    score[b*NT + i] = dp * di;
  }
}

// ---------------- topk: hybrid bitonic sort 4096 (score desc, idx asc) ----------------
__device__ __forceinline__ bool kv_lt(float s1, int a1, float s2, int a2){
  return (s1 > s2) || (s1 == s2 && a1 < a2);
}
#define KV_CMPX(sx,ax,sy,ay,up) do{ bool _l = kv_lt(sx,ax,sy,ay); \
  if (_l != (up)) { float _ts=sx; sx=sy; sy=_ts; int _ta=ax; ax=ay; ay=_ta; } }while(0)
#define KV_TAKE(sx,ax,ps,pa,eqd) do{ bool _keep = kv_lt(sx,ax,ps,pa) == (eqd); \
  if(!_keep){ sx=(ps); ax=(pa); } }while(0)

__global__ __launch_bounds__(1024) void topk_all(const float* __restrict__ score, int* __restrict__ idx_down,
                                                 int* __restrict__ inv, int b_base){
  __shared__ float ss[4096];
  __shared__ int ii[4096];
  int b = b_base + blockIdx.x;
  int t = threadIdx.x;
  float s0,s1,s2,s3; int a0,a1,a2,a3;
  {
    float4 v = *(const float4*)(score + b*NT + 4*t);
    s0=v.x; s1=v.y; s2=v.z; s3=v.w;
    a0=4*t; a1=4*t+1; a2=4*t+2; a3=4*t+3;
    int4 mi; mi.x=-1; mi.y=-1; mi.z=-1; mi.w=-1;
    *(int4*)(inv + b*NT + 4*t) = mi;
  }
  for (int k = 2; k <= 4096; k <<= 1){
    bool upT = ((4*t) & k) == 0;
    for (int j = k >> 1; j >= 256; j >>= 1){
      __syncthreads();
      float4 sv; sv.x=s0; sv.y=s1; sv.z=s2; sv.w=s3;
      int4 av; av.x=a0; av.y=a1; av.z=a2; av.w=a3;
      *(float4*)&ss[4*t] = sv;
      *(int4*)&ii[4*t] = av;
      __syncthreads();
      int pt = t ^ (j >> 2);
      bool eqd = ((t & (j >> 2)) == 0) == upT;
      float4 ps = *(const float4*)&ss[4*pt];
      int4  pa = *(const int4*)&ii[4*pt];
      KV_TAKE(s0,a0,ps.x,pa.x,eqd);
      KV_TAKE(s1,a1,ps.y,pa.y,eqd);
      KV_TAKE(s2,a2,ps.z,pa.z,eqd);
      KV_TAKE(s3,a3,ps.w,pa.w,eqd);
    }
    int jhi = (k >> 1) < 128 ? (k >> 1) : 128;
    for (int j = jhi; j >= 4; j >>= 1){
      int dl = j >> 2;
      bool eqd = ((t & dl) == 0) == upT;
      { float ps=__shfl_xor(s0,dl,64); int pa=__shfl_xor(a0,dl,64); KV_TAKE(s0,a0,ps,pa,eqd); }
      { float ps=__shfl_xor(s1,dl,64); int pa=__shfl_xor(a1,dl,64); KV_TAKE(s1,a1,ps,pa,eqd); }
      { float ps=__shfl_xor(s2,dl,64); int pa=__shfl_xor(a2,dl,64); KV_TAKE(s2,a2,ps,pa,eqd); }
      { float ps=__shfl_xor(s3,dl,64); int pa=__shfl_xor(a3,dl,64); KV_TAKE(s3,a3,ps,pa,eqd); }
    }
    if (k >= 4){
      KV_CMPX(s0,a0,s2,a2,upT);
      KV_CMPX(s1,a1,s3,a3,upT);
      KV_CMPX(s0,a0,s1,a1,upT);
      KV_CMPX(s2,a2,s3,a3,upT);
    } else {
      KV_CMPX(s0,a0,s1,a1,true);
      KV_CMPX(s2,a2,s3,a3,false);
    }
  }
  __syncthreads();
  if (t < 256){
    int tok;
    tok = a0; idx_down[b*MC + 4*t + 0] = tok; inv[b*NT + tok] = 4*t + 0;
    tok = a1; idx_down[b*MC + 4*t + 1] = tok; inv[b*NT + tok] = 4*t + 1;
    tok = a2; idx_down[b*MC + 4*t + 2] = tok; inv[b*NT + tok] = 4*t + 2;
    tok = a3; idx_down[b*MC + 4*t + 3] = tok; inv[b*NT + tok] = 4*t + 3;
  }
}

// assign: block = 16 j x 16 m-chunks (64 m each, ascending); grid 256 x gy.
__global__ __launch_bounds__(256) void assign_all(const float* __restrict__ G, size_t gstride,
                                                  const float* __restrict__ sq,
                                                  const int* __restrict__ idx_down, const int* __restrict__ inv,
                                                  const float* __restrict__ wt,
                                                  int* __restrict__ idx_cluster, float* __restrict__ allw,
                                                  int b_base){
  int b = b_base + blockIdx.y;
  const float* Gb = G + (size_t)blockIdx.y*gstride;
  int jl = threadIdx.x & 15, mq = threadIdx.x >> 4;
  int j = blockIdx.x * 16 + jl;
  const float* sqb = sq + b*NT;
  float sqj = sqb[j];
  const int* idb = idx_down + b*MC;
  float bestd = INFINITY; int bestm = 0x7fffffff;
  for (int m = mq*64; m < mq*64 + 64; ++m){
    int im = idb[m];
    float g = Gb[(size_t)im*NT + j];
    float v = fmaxf(sqb[im] + sqj - 2.0f*g, 0.0f);
    float d = sqrtf(v) * 0.0625f;
    if (d < bestd){ bestd = d; bestm = m; }
  }
  __shared__ float ld[16][17];
  __shared__ int lm[16][17];
  ld[mq][jl] = bestd; lm[mq][jl] = bestm;
  __syncthreads();
  if (mq == 0){
    for (int q = 1; q < 16; ++q){
      float d2 = ld[q][jl]; int m2 = lm[q][jl];
      if (d2 < bestd || (d2 == bestd && m2 < bestm)){ bestd = d2; bestm = m2; }
    }
    int iv = inv[b*NT + j];
    int final_m = (iv >= 0) ? iv : bestm;
    idx_cluster[b*NT + j] = final_m;
    atomicAdd(&allw[b*MC + final_m], wt[b*NT + j]);
  }
}

// ---------------- merge + outputs ----------------
__global__ __launch_bounds__(256) void xdown_kernel(const int* __restrict__ idx_cluster,
                                                    const float* __restrict__ wt, const float* __restrict__ allw,
                                                    const float* __restrict__ xt, float* __restrict__ out0){
  int bn = blockIdx.x;
  int d = threadIdx.x;
  int b = bn >> 12;
  int ic = idx_cluster[bn];
  float nw = wt[bn] / (allw[b*MC + ic] + EPS_F);
  float v = xt[(size_t)bn*DOUT + d] * nw;
  atomicAdd(&out0[((size_t)(b*MC + ic))*DOUT + d], v);
}
__global__ __launch_bounds__(256) void out12a_kernel(const int* __restrict__ idx_agg, const int* __restrict__ idx_cluster,
                                                     const float* __restrict__ aggw,
                                                     const float* __restrict__ wt, const float* __restrict__ allw,
                                                     float* __restrict__ awd, int* __restrict__ awdmax,
                                                     float* __restrict__ out1){
  __shared__ float red[4];
  int lin = blockIdx.x * 256 + threadIdx.x;
  int b = lin >> 12;
  int ia = idx_agg[lin];
  int ic = idx_cluster[b*NT + ia];
  out1[lin] = (float)ic;
  float nw = wt[b*NT + ia] / (allw[b*MC + ic] + EPS_F);
  float v = aggw[lin] * nw;
  awd[lin] = v;
  float wv = v;
#pragma unroll
  for (int m = 1; m < 64; m <<= 1) wv = fmaxf(wv, __shfl_xor(wv, m, 64));
  int lane = threadIdx.x & 63, wid = threadIdx.x >> 6;
  if (lane == 0) red[wid] = wv;
  __syncthreads();
  if (threadIdx.x == 0){
    float bm = fmaxf(fmaxf(red[0], red[1]), fmaxf(red[2], red[3]));
    atomicMax(&awdmax[b], __float_as_int(bm));
  }
}
__global__ __launch_bounds__(256) void out2_kernel(const float* __restrict__ awd, const int* __restrict__ awdmax,
                                                   float* __restrict__ out2){
  int lin = blockIdx.x * 256 + threadIdx.x;
  int b = lin >> 12;
  out2[lin] = awd[lin] / __int_as_float(awdmax[b]);
}

extern "C" void kernel_launch(void* const* d_in, const int* in_sizes, int n_in,
                              void* d_out, int out_size, void* d_ws, size_t ws_size,
                              hipStream_t stream) {
  const float* x      = (const float*)d_in[0];
  const float* loc    = (const float*)d_in[1];
  const int*   idxagg = (const int*)d_in[2];
  const float* aggw   = (const float*)d_in[3];
  const float* convw  = (const float*)d_in[7];
  const float* convb  = (const float*)d_in[8];
  const float* skipw  = (const float*)d_in[9];
  const float* lng    = (const float*)d_in[10];
  const float* lnb    = (const float*)d_in[11];
  const float* confw  = (const float*)d_in[12];
  const float* confb  = (const float*)d_in[13];

  char* ws = (char*)d_ws;
  float* w_xmap  = (float*)(ws + OFF_XMAP);
  float* w_cnt   = (float*)(ws + OFF_CNT);
  float* w_tot   = (float*)(ws + OFF_TOT);
  float* w_allw  = (float*)(ws + OFF_ALLW);
  int*   w_vmax  = (int*)  (ws + OFF_VMAX);
  int*   w_awdm  = (int*)  (ws + OFF_AWDM);
  float* w_ymap  = (float*)(ws + OFF_YMAP);
  float* w_xt    = (float*)(ws + OFF_XT);
  float* w_sq    = (float*)(ws + OFF_SQ);
  float* w_den   = (float*)(ws + OFF_DEN);
  float* w_score = (float*)(ws + OFF_SCORE);
  float* w_wt    = (float*)(ws + OFF_WT);
  float* w_awd   = (float*)(ws + OFF_AWD);
  int*   w_idxd  = (int*)  (ws + OFF_IDXD);
  int*   w_idxc  = (int*)  (ws + OFF_IDXC);
  int*   w_inv   = (int*)  (ws + OFF_INV);
  float* w_wtr   = (float*)(ws + OFF_WTR);
  float* w_swt   = (float*)(ws + OFF_SWT);
  float* w_p     = (float*)(ws + OFF_P);
  u16*   w_xh    = (u16*)  (ws + OFF_XH);
  u16*   w_xm    = (u16*)  (ws + OFF_XM);
  u16*   w_xl    = (u16*)  (ws + OFF_XL);
  float* w_g     = (float*)(ws + OFF_G);
  float* w_dpart = (float*)(ws + OFF_P);   // aliases P (dead after conv_gemm)

  int gcount = 1;
  for (int k = 4; k >= 1; --k){
    if (OFF_G + (size_t)k*GSZB <= ws_size){ gcount = k; break; }
  }

  float* out0 = (float*)d_out;
  float* out1 = out0 + NB*MC*DOUT;
  float* out2 = out1 + NB*NT;

  hipMemsetAsync(ws, 0, ZERO_BYTES, stream);
  hipMemsetAsync(out0, 0, (size_t)NB*MC*DOUT*sizeof(float), stream);

  t2m_scatter<<<NB*NT*CI/256, 256, 0, stream>>>(x, loc, idxagg, aggw, w_xmap, w_cnt, w_tot);
  wprep_kernel<<<1280, 256, 0, stream>>>(convw, skipw, w_wtr, w_swt);
  im2col_kernel<<<2048, 256, 0, stream>>>(w_xmap, w_cnt, w_p);
  conv_gemm<<<dim3(64, 8), 256, 0, stream>>>(w_p, w_wtr, convb, w_ymap);
  skip_kernel<<<NB*NT/8, 256, 0, stream>>>(x, w_swt, w_xt);
  m2t_scatter<<<NB*NT, 256, 0, stream>>>(w_ymap, loc, idxagg, aggw, w_tot, w_xt);
  ln_kernel<<<NB*NT, 256, 0, stream>>>(w_xt, lng, lnb, confw, confb, w_sq, w_wt);
  xsplit_kernel<<<NB*NT*DOUT/512, 256, 0, stream>>>(w_xt, w_xh, w_xm, w_xl);

  for (int g0 = 0; g0 < NB; g0 += gcount){
    int gy = (NB - g0 < gcount) ? (NB - g0) : gcount;
    gram_mfma  <<<dim3(528, gy), 256, 0, stream>>>(w_xh, w_xm, w_xl, w_sq, w_g, w_dpart, g0, GSZ);
    dens_merge <<<dim3(16, gy), 256, 0, stream>>>(w_dpart, w_den, w_vmax, g0);
    parent_all <<<dim3(1024, gy), 256, 0, stream>>>(w_g, GSZ, w_sq, w_den, w_vmax, w_score, g0);
    topk_all   <<<gy, 1024, 0, stream>>>(w_score, w_idxd, w_inv, g0);
    assign_all <<<dim3(256, gy), 256, 0, stream>>>(w_g, GSZ, w_sq, w_idxd, w_inv, w_wt, w_idxc, w_allw, g0);
  }

  xdown_kernel<<<NB*NT, 256, 0, stream>>>(w_idxc, w_wt, w_allw, w_xt, out0);
  out12a_kernel<<<NB*NT/256, 256, 0, stream>>>(idxagg, w_idxc, aggw, w_wt, w_allw, w_awd, w_awdm, out1);
  out2_kernel<<<NB*NT/256, 256, 0, stream>>>(w_awd, w_awdm, out2);

  (void)in_sizes; (void)n_in; (void)out_size;
}